// Round 11
// baseline (1426.752 us; speedup 1.0000x reference)
//
#include <hip/hip_runtime.h>
#include <math.h>

#define N_NODES 50000
#define N_EDGES 800000
#define N_GRAPHS 128
#define IN_CH 256
#define HID 64
#define HEADS 4
#define OUT_CH 16
#define NSLOT 32

typedef unsigned short ushort_t;
typedef unsigned int uint_t;
typedef unsigned char uchar_t;
typedef __attribute__((ext_vector_type(8))) short bf16x8;
typedef __attribute__((ext_vector_type(4))) float f32x4;
typedef __attribute__((ext_vector_type(2))) float f32x2;

// ---------------- workspace layout (bytes, 64-aligned) ----------------
static const size_t OFF_XB     = 0;           // x bf16       25,600,000
static const size_t OFF_H1F8   = 25600000;    // h1 fp8       12,800,000
static const size_t OFF_OUT1B  = 38400000;    // out1 bf16    25,600,000
static const size_t OFF_H2F8   = 64000000;    // h2 fp8        3,200,000
static const size_t OFF_A1S    = 67200000;    //                 800,000
static const size_t OFF_A1D    = 68000000;    //                 800,000
static const size_t OFF_A2S    = 68800000;    //                 200,000
static const size_t OFF_A2D    = 69000000;    //                 200,000
// cnt + slots + done contiguous -> ONE memset
static const size_t OFF_CNT    = 69200000;    //                 200,000
static const size_t OFF_SLOTS  = 69400000;    //               1,048,576
static const size_t OFF_DONE   = 70448576;    //                      64
static const size_t OFF_ROWPTR = 70448640;    //                 200,064
static const size_t OFF_CURSOR = 70648704;    //                 200,000
static const size_t OFF_CSR    = 70848704;    //               3,200,000
static const size_t OFF_PART   = 74048704;    //                   1,024
static const size_t OFF_W1T    = 74049728;    //                 131,072
static const size_t OFF_W2T    = 74180800;    //                  32,768

#define DEV static __device__ __forceinline__

DEV float leaky02(float v) { return v > 0.f ? v : 0.2f * v; }
DEV float bf2f(ushort_t s) { return __uint_as_float(((uint_t)s) << 16); }
DEV ushort_t f2bf(float f) {
    uint_t u = __float_as_uint(f);
    return (ushort_t)((u + 0x7FFFu + ((u >> 16) & 1u)) >> 16);
}
DEV uchar_t f2fp8(float f) {
    int p = __builtin_amdgcn_cvt_pk_fp8_f32(f, 0.f, 0, false);
    return (uchar_t)(p & 0xFF);
}
DEV void dec16(uint4 v, float* o) {
    f32x2 t;
    t = __builtin_amdgcn_cvt_pk_f32_fp8(v.x, false); o[0]  = t[0]; o[1]  = t[1];
    t = __builtin_amdgcn_cvt_pk_f32_fp8(v.x, true);  o[2]  = t[0]; o[3]  = t[1];
    t = __builtin_amdgcn_cvt_pk_f32_fp8(v.y, false); o[4]  = t[0]; o[5]  = t[1];
    t = __builtin_amdgcn_cvt_pk_f32_fp8(v.y, true);  o[6]  = t[0]; o[7]  = t[1];
    t = __builtin_amdgcn_cvt_pk_f32_fp8(v.z, false); o[8]  = t[0]; o[9]  = t[1];
    t = __builtin_amdgcn_cvt_pk_f32_fp8(v.z, true);  o[10] = t[0]; o[11] = t[1];
    t = __builtin_amdgcn_cvt_pk_f32_fp8(v.w, false); o[12] = t[0]; o[13] = t[1];
    t = __builtin_amdgcn_cvt_pk_f32_fp8(v.w, true);  o[14] = t[0]; o[15] = t[1];
}
DEV int wred_sum_i(int v) {
    #pragma unroll
    for (int o = 32; o; o >>= 1) v += __shfl_xor(v, o, 64);
    return v;
}
DEV int lower_bound_i(const int* a, int n, int key) {
    int lo = 0, hi = n;
    while (lo < hi) { int mid = (lo + hi) >> 1; if (a[mid] < key) lo = mid + 1; else hi = mid; }
    return lo;
}
DEV void gload_lds16(const void* g, void* l) {
    __builtin_amdgcn_global_load_lds(
        (const __attribute__((address_space(1))) uint_t*)g,
        (__attribute__((address_space(3))) uint_t*)l, 16, 0, 0);
}

// ---------------- fused prep: x->bf16, weights->bf16^T, degree count --------
__global__ void prep_all(const float* __restrict__ x, ushort_t* __restrict__ xb,
                         const float* __restrict__ g1w, const float* __restrict__ g2w,
                         ushort_t* __restrict__ w1t, ushort_t* __restrict__ w2t,
                         const int* __restrict__ ei, int* __restrict__ cnt) {
    int tid = blockIdx.x * 256 + threadIdx.x;     // 3,200,000 threads
    {   // convert x, one float4 per thread
        float4 v = *reinterpret_cast<const float4*>(&x[(size_t)tid * 4]);
        ushort4 o;
        o.x = f2bf(v.x); o.y = f2bf(v.y); o.z = f2bf(v.z); o.w = f2bf(v.w);
        *reinterpret_cast<ushort4*>(&xb[(size_t)tid * 4]) = o;
    }
    if (tid < N_EDGES) atomicAdd(&cnt[ei[N_EDGES + tid]], 1);
    if (tid < 256 * 256) {                        // w1t[n][k] = g1w[k][n]
        int n = tid >> 8, k = tid & 255;
        w1t[tid] = f2bf(g1w[k * 256 + n]);
    }
    if (tid < 64 * 256) {                         // w2t[n][k] = g2w[k][n]
        int n = tid >> 8, k = tid & 255;
        w2t[tid] = f2bf(g2w[k * 64 + n]);
    }
}

// ---------------- CSR build: 2-kernel scan ----------------------------------
__global__ void scan_partial(const int* __restrict__ cnt, int* __restrict__ part) {
    __shared__ int wsum[4];
    int i = blockIdx.x * 256 + threadIdx.x;
    int v = (i < N_NODES) ? cnt[i] : 0;
    v = wred_sum_i(v);
    if ((threadIdx.x & 63) == 0) wsum[threadIdx.x >> 6] = v;
    __syncthreads();
    if (threadIdx.x == 0) part[blockIdx.x] = wsum[0] + wsum[1] + wsum[2] + wsum[3];
}

__global__ void scan_final2(const int* __restrict__ cnt, const int* __restrict__ part,
                            int* __restrict__ rowptr, int* __restrict__ cursor, int npart) {
    __shared__ int buf[256];
    __shared__ int ws4[4];
    int b = blockIdx.x, tid = threadIdx.x;
    int pv = (tid < b && tid < npart) ? part[tid] : 0;
    pv = wred_sum_i(pv);
    if ((tid & 63) == 0) ws4[tid >> 6] = pv;
    __syncthreads();
    int base = ws4[0] + ws4[1] + ws4[2] + ws4[3];
    int i = b * 256 + tid;
    int v = (i < N_NODES) ? cnt[i] : 0;
    buf[tid] = v; __syncthreads();
    for (int off = 1; off < 256; off <<= 1) {
        int t = (tid >= off) ? buf[tid - off] : 0;
        __syncthreads();
        buf[tid] += t;
        __syncthreads();
    }
    if (i < N_NODES) {
        int incl = buf[tid] + base;
        rowptr[i + 1] = incl;
        cursor[i] = incl - v;
    }
    if (i == 0) rowptr[0] = 0;
}

__global__ void scatter_kernel(const int* __restrict__ ei, int* __restrict__ cursor,
                               int* __restrict__ csr) {
    int e = blockIdx.x * blockDim.x + threadIdx.x;
    if (e < N_EDGES) {
        int d = ei[N_EDGES + e];
        int pos = atomicAdd(&cursor[d], 1);
        csr[pos] = ei[e];
    }
}

// ---------------- GEMM1: 128x128 tile, swizzled LDS, fp8 C, fused logits ----
__global__ __launch_bounds__(256) void gemm1_swz(
    const ushort_t* __restrict__ A, const ushort_t* __restrict__ Bt,
    uchar_t* __restrict__ C8, int M,
    const float* __restrict__ att_src, const float* __restrict__ att_dst,
    float* __restrict__ as_out, float* __restrict__ ad_out) {
    __shared__ ushort_t As[128 * 64];
    __shared__ ushort_t Bs[128 * 64];
    const int tid = threadIdx.x;
    const int w = tid >> 6, lane = tid & 63;
    const int lr = lane & 15, lg = lane >> 4;
    const int m0 = (blockIdx.x >> 1) * 128, n0 = (blockIdx.x & 1) * 128;
    const int wm = (w >> 1) * 64, wn = (w & 1) * 64;
    f32x4 acc[4][4];
    #pragma unroll
    for (int i = 0; i < 4; ++i)
        #pragma unroll
        for (int j = 0; j < 4; ++j) acc[i][j] = (f32x4){0.f, 0.f, 0.f, 0.f};

    const int rsub = lane >> 3;
    const int gc = (lane & 7) ^ rsub;

    for (int k0 = 0; k0 < 256; k0 += 64) {
        #pragma unroll
        for (int t = 0; t < 4; ++t) {
            int slot = t * 4 + w;
            int row = slot * 8 + rsub;
            int gm = m0 + row; if (gm > M - 1) gm = M - 1;
            gload_lds16((const char*)A + (size_t)gm * 512 + k0 * 2 + gc * 16,
                        (char*)As + slot * 1024);
        }
        #pragma unroll
        for (int t = 0; t < 4; ++t) {
            int slot = t * 4 + w;
            int row = slot * 8 + rsub;
            gload_lds16((const char*)Bt + (size_t)(n0 + row) * 512 + k0 * 2 + gc * 16,
                        (char*)Bs + slot * 1024);
        }
        __syncthreads();
        #pragma unroll
        for (int kk = 0; kk < 2; ++kk) {
            const int chunk = kk * 4 + lg;
            bf16x8 av[4], bv[4];
            #pragma unroll
            for (int mf = 0; mf < 4; ++mf) {
                int row = wm + mf * 16 + lr;
                av[mf] = *reinterpret_cast<const bf16x8*>(&As[row * 64 + ((chunk ^ (row & 7)) * 8)]);
            }
            #pragma unroll
            for (int nf = 0; nf < 4; ++nf) {
                int row = wn + nf * 16 + lr;
                bv[nf] = *reinterpret_cast<const bf16x8*>(&Bs[row * 64 + ((chunk ^ (row & 7)) * 8)]);
            }
            #pragma unroll
            for (int mf = 0; mf < 4; ++mf)
                #pragma unroll
                for (int nf = 0; nf < 4; ++nf)
                    acc[mf][nf] = __builtin_amdgcn_mfma_f32_16x16x32_bf16(av[mf], bv[nf], acc[mf][nf], 0, 0, 0);
        }
        __syncthreads();
    }
    #pragma unroll
    for (int mf = 0; mf < 4; ++mf)
        #pragma unroll
        for (int nf = 0; nf < 4; ++nf)
            #pragma unroll
            for (int r = 0; r < 4; ++r) {
                int row = m0 + wm + mf * 16 + lg * 4 + r;
                int col = n0 + wn + nf * 16 + lr;
                if (row < M) C8[(size_t)row * 256 + col] = f2fp8(acc[mf][nf][r]);
            }
    {   // fused att logits (head = 64-col slice, wave-exclusive), full precision
        float asr[4], adr[4];
        #pragma unroll
        for (int nf = 0; nf < 4; ++nf) {
            int col = n0 + wn + nf * 16 + lr;
            asr[nf] = att_src[col];
            adr[nf] = att_dst[col];
        }
        const int hidx = (n0 + wn) >> 6;
        #pragma unroll
        for (int mf = 0; mf < 4; ++mf)
            #pragma unroll
            for (int r = 0; r < 4; ++r) {
                float s = 0.f, d = 0.f;
                #pragma unroll
                for (int nf = 0; nf < 4; ++nf) {
                    float v = acc[mf][nf][r];
                    s += v * asr[nf]; d += v * adr[nf];
                }
                #pragma unroll
                for (int o = 8; o; o >>= 1) {
                    s += __shfl_xor(s, o, 64);
                    d += __shfl_xor(d, o, 64);
                }
                int row = m0 + wm + mf * 16 + lg * 4 + r;
                if (lr == 0 && row < M) {
                    as_out[row * 4 + hidx] = s;
                    ad_out[row * 4 + hidx] = d;
                }
            }
    }
}

// ---------------- GEMM2 (BN=64), fp8 C, fused att logits --------------------
__global__ __launch_bounds__(256) void gemm2_swz(
    const ushort_t* __restrict__ A, const ushort_t* __restrict__ Bt,
    uchar_t* __restrict__ C8, int M,
    const float* __restrict__ att_src, const float* __restrict__ att_dst,
    float* __restrict__ as_out, float* __restrict__ ad_out) {
    __shared__ ushort_t As[128 * 64];
    __shared__ ushort_t Bs[64 * 64];
    const int tid = threadIdx.x;
    const int w = tid >> 6, lane = tid & 63;
    const int lr = lane & 15, lg = lane >> 4;
    const int m0 = blockIdx.x * 128;
    const int wm = w * 32;
    f32x4 acc[2][4];
    #pragma unroll
    for (int i = 0; i < 2; ++i)
        #pragma unroll
        for (int j = 0; j < 4; ++j) acc[i][j] = (f32x4){0.f, 0.f, 0.f, 0.f};

    const int rsub = lane >> 3;
    const int gc = (lane & 7) ^ rsub;

    for (int k0 = 0; k0 < 256; k0 += 64) {
        #pragma unroll
        for (int t = 0; t < 4; ++t) {
            int slot = t * 4 + w;
            int row = slot * 8 + rsub;
            int gm = m0 + row; if (gm > M - 1) gm = M - 1;
            gload_lds16((const char*)A + (size_t)gm * 512 + k0 * 2 + gc * 16,
                        (char*)As + slot * 1024);
        }
        #pragma unroll
        for (int t = 0; t < 2; ++t) {
            int slot = t * 4 + w;
            int row = slot * 8 + rsub;
            gload_lds16((const char*)Bt + (size_t)row * 512 + k0 * 2 + gc * 16,
                        (char*)Bs + slot * 1024);
        }
        __syncthreads();
        #pragma unroll
        for (int kk = 0; kk < 2; ++kk) {
            const int chunk = kk * 4 + lg;
            bf16x8 av[2], bv[4];
            #pragma unroll
            for (int mf = 0; mf < 2; ++mf) {
                int row = wm + mf * 16 + lr;
                av[mf] = *reinterpret_cast<const bf16x8*>(&As[row * 64 + ((chunk ^ (row & 7)) * 8)]);
            }
            #pragma unroll
            for (int nf = 0; nf < 4; ++nf) {
                int row = nf * 16 + lr;
                bv[nf] = *reinterpret_cast<const bf16x8*>(&Bs[row * 64 + ((chunk ^ (row & 7)) * 8)]);
            }
            #pragma unroll
            for (int mf = 0; mf < 2; ++mf)
                #pragma unroll
                for (int nf = 0; nf < 4; ++nf)
                    acc[mf][nf] = __builtin_amdgcn_mfma_f32_16x16x32_bf16(av[mf], bv[nf], acc[mf][nf], 0, 0, 0);
        }
        __syncthreads();
    }
    #pragma unroll
    for (int mf = 0; mf < 2; ++mf)
        #pragma unroll
        for (int nf = 0; nf < 4; ++nf)
            #pragma unroll
            for (int r = 0; r < 4; ++r) {
                int row = m0 + wm + mf * 16 + lg * 4 + r;
                int col = nf * 16 + lr;
                if (row < M) C8[(size_t)row * 64 + col] = f2fp8(acc[mf][nf][r]);
            }
    {
        float asr[4], adr[4];
        #pragma unroll
        for (int nf = 0; nf < 4; ++nf) {
            asr[nf] = att_src[nf * 16 + lr];
            adr[nf] = att_dst[nf * 16 + lr];
        }
        #pragma unroll
        for (int mf = 0; mf < 2; ++mf)
            #pragma unroll
            for (int r = 0; r < 4; ++r) {
                float s = 0.f, d = 0.f;
                #pragma unroll
                for (int nf = 0; nf < 4; ++nf) {
                    float v = acc[mf][nf][r];
                    s += v * asr[nf]; d += v * adr[nf];
                }
                #pragma unroll
                for (int o = 8; o; o >>= 1) {
                    s += __shfl_xor(s, o, 64);
                    d += __shfl_xor(d, o, 64);
                }
                int row = m0 + wm + mf * 16 + lg * 4 + r;
                if (lr == 0 && row < M) { as_out[row] = s; ad_out[row] = d; }
            }
    }
}

// ---------------- GAT1: 4-edge groups x 16 lanes x uint4 (16ch/lane) --------
// lane = g*16 + j16 : group g handles edge e+jj*4+g; lane holds channels
// [j16*16, j16*16+16) (all in head j16>>2). 16 edges in flight per wave.
// Cross-group combine via shfl_xor(16),(32); self-loop & store in group 0.
__global__ void gat1_agg(const uint_t* __restrict__ h1u, const float* __restrict__ a1s,
                         const float* __restrict__ a1d, const int* __restrict__ rowptr,
                         const int* __restrict__ csr, const float* __restrict__ bias,
                         ushort_t* __restrict__ out1b) {
    const uint4* h1q = (const uint4*)h1u;
    int w = threadIdx.x >> 6;
    int i = blockIdx.x * 4 + w;                // N_NODES = 4*12500 exactly
    int lane = threadIdx.x & 63;
    int g = lane >> 4, j16 = lane & 15;
    int hd = j16 >> 2;
    int beg = rowptr[i], end = rowptr[i + 1];
    float ad = a1d[i * 4 + hd];
    float acc[16];
    float den = 0.f;
    #pragma unroll
    for (int k = 0; k < 16; ++k) acc[k] = 0.f;
    if (g == 0) {   // self loop counted once
        float p = __expf(leaky02(a1s[i * 4 + hd] + ad));
        float hv[16];
        dec16(h1q[(uint_t)i * 16 + j16], hv);
        den = p;
        #pragma unroll
        for (int k = 0; k < 16; ++k) acc[k] = p * hv[k];
    }
    for (int e = beg; e < end; e += 16) {
        int s[4]; float q[4]; uint4 v[4];
        #pragma unroll
        for (int jj = 0; jj < 4; ++jj) {
            int idx = e + jj * 4 + g;
            s[jj] = (idx < end) ? csr[idx] : i;
        }
        #pragma unroll
        for (int jj = 0; jj < 4; ++jj)
            v[jj] = h1q[(uint_t)s[jj] * 16 + j16];      // issue gathers early
        #pragma unroll
        for (int jj = 0; jj < 4; ++jj) {
            int idx = e + jj * 4 + g;
            q[jj] = (idx < end) ? __expf(leaky02(a1s[(uint_t)s[jj] * 4 + hd] + ad)) : 0.f;
        }
        #pragma unroll
        for (int jj = 0; jj < 4; ++jj) {
            float hv[16];
            dec16(v[jj], hv);
            den += q[jj];
            #pragma unroll
            for (int k = 0; k < 16; ++k) acc[k] += q[jj] * hv[k];
        }
    }
    den += __shfl_xor(den, 16, 64); den += __shfl_xor(den, 32, 64);
    #pragma unroll
    for (int k = 0; k < 16; ++k) {
        acc[k] += __shfl_xor(acc[k], 16, 64);
        acc[k] += __shfl_xor(acc[k], 32, 64);
    }
    if (g == 0) {
        float inv = 1.f / (den + 1e-16f);
        ushort_t tmp[16];
        #pragma unroll
        for (int k4 = 0; k4 < 4; ++k4) {
            float4 bv = *reinterpret_cast<const float4*>(&bias[j16 * 16 + k4 * 4]);
            tmp[k4 * 4 + 0] = f2bf(fmaxf(acc[k4 * 4 + 0] * inv + bv.x, 0.f));
            tmp[k4 * 4 + 1] = f2bf(fmaxf(acc[k4 * 4 + 1] * inv + bv.y, 0.f));
            tmp[k4 * 4 + 2] = f2bf(fmaxf(acc[k4 * 4 + 2] * inv + bv.z, 0.f));
            tmp[k4 * 4 + 3] = f2bf(fmaxf(acc[k4 * 4 + 3] * inv + bv.w, 0.f));
        }
        *reinterpret_cast<uint4*>(&out1b[(size_t)i * 256 + j16 * 16])     = *reinterpret_cast<uint4*>(&tmp[0]);
        *reinterpret_cast<uint4*>(&out1b[(size_t)i * 256 + j16 * 16 + 8]) = *reinterpret_cast<uint4*>(&tmp[8]);
    }
}

// ---------------- GAT2 + pool + tail-block classifier -----------------------
__global__ void gat2_agg_pool(const uint_t* __restrict__ h2u, const float* __restrict__ a2s,
                              const float* __restrict__ a2d, const int* __restrict__ rowptr,
                              const int* __restrict__ csr, const float* __restrict__ bias,
                              const int* __restrict__ batch, float* __restrict__ slots,
                              int* __restrict__ done,
                              const float* __restrict__ w1, const float* __restrict__ b1,
                              const float* __restrict__ w2, const float* __restrict__ b2,
                              float* __restrict__ out) {
    __shared__ float fv[4][64];
    __shared__ int bg[4];
    __shared__ int lastFlag;
    int w = threadIdx.x >> 6;
    int i = blockIdx.x * 4 + w;                // N_NODES = 4*12500 exactly
    int lane = threadIdx.x & 63;
    int g = lane >> 4, c = lane & 15;
    int beg = rowptr[i], end = rowptr[i + 1];
    float ad = a2d[i];
    float acc0 = 0.f, acc1 = 0.f, acc2 = 0.f, acc3 = 0.f, qsum = 0.f;
    if (g == 0) {   // self loop counted once
        float p = __expf(leaky02(a2s[i] + ad));
        uint_t v = h2u[(size_t)i * 16 + c];
        f32x2 lo = __builtin_amdgcn_cvt_pk_f32_fp8(v, false);
        f32x2 hi = __builtin_amdgcn_cvt_pk_f32_fp8(v, true);
        qsum = p;
        acc0 = p * lo[0]; acc1 = p * lo[1]; acc2 = p * hi[0]; acc3 = p * hi[1];
    }
    for (int e = beg; e < end; e += 16) {
        int  s[4]; float q[4]; uint_t hv[4];
        #pragma unroll
        for (int j = 0; j < 4; ++j) {
            int idx = e + j * 4 + g;
            s[j] = (idx < end) ? csr[idx] : i;
        }
        #pragma unroll
        for (int j = 0; j < 4; ++j) hv[j] = h2u[(size_t)s[j] * 16 + c];
        #pragma unroll
        for (int j = 0; j < 4; ++j) {
            int idx = e + j * 4 + g;
            q[j] = (idx < end) ? __expf(leaky02(a2s[s[j]] + ad)) : 0.f;
        }
        #pragma unroll
        for (int j = 0; j < 4; ++j) {
            f32x2 lo = __builtin_amdgcn_cvt_pk_f32_fp8(hv[j], false);
            f32x2 hi = __builtin_amdgcn_cvt_pk_f32_fp8(hv[j], true);
            qsum += q[j];
            acc0 += q[j] * lo[0]; acc1 += q[j] * lo[1];
            acc2 += q[j] * hi[0]; acc3 += q[j] * hi[1];
        }
    }
    qsum += __shfl_xor(qsum, 16, 64); qsum += __shfl_xor(qsum, 32, 64);
    acc0 += __shfl_xor(acc0, 16, 64); acc0 += __shfl_xor(acc0, 32, 64);
    acc1 += __shfl_xor(acc1, 16, 64); acc1 += __shfl_xor(acc1, 32, 64);
    acc2 += __shfl_xor(acc2, 16, 64); acc2 += __shfl_xor(acc2, 32, 64);
    acc3 += __shfl_xor(acc3, 16, 64); acc3 += __shfl_xor(acc3, 32, 64);
    if (g == 0) {
        float inv = 1.f / (qsum + 1e-16f);
        fv[w][c * 4 + 0] = fmaxf(acc0 * inv + bias[c * 4 + 0], 0.f);
        fv[w][c * 4 + 1] = fmaxf(acc1 * inv + bias[c * 4 + 1], 0.f);
        fv[w][c * 4 + 2] = fmaxf(acc2 * inv + bias[c * 4 + 2], 0.f);
        fv[w][c * 4 + 3] = fmaxf(acc3 * inv + bias[c * 4 + 3], 0.f);
        if (c == 0) bg[w] = batch[i];
    }
    __syncthreads();
    if (w == 0) {
        int slot = blockIdx.x & (NSLOT - 1);
        int g0 = bg[0];
        float s = 0.f;
        #pragma unroll
        for (int r = 0; r < 4; ++r) if (bg[r] == g0) s += fv[r][lane];
        atomicAdd(&slots[((size_t)g0 * NSLOT + slot) * 64 + lane], s);
        #pragma unroll
        for (int r = 1; r < 4; ++r)
            if (bg[r] != g0)
                atomicAdd(&slots[((size_t)bg[r] * NSLOT + slot) * 64 + lane], fv[r][lane]);
    }
    // ---- tail block: classifier (threadfence + completion counter) ----
    __threadfence();
    if (threadIdx.x == 0) lastFlag = (atomicAdd(done, 1) == (int)gridDim.x - 1);
    __syncthreads();
    if (!lastFlag) return;
    __shared__ float pb[4][64];
    __shared__ float hb[4][32];
    for (int gr = w; gr < N_GRAPHS; gr += 4) {   // 1 graph per wave, 32 rounds
        float s = 0.f;
        #pragma unroll
        for (int sl = 0; sl < NSLOT; ++sl) s += slots[((size_t)gr * NSLOT + sl) * 64 + lane];
        int lo = lower_bound_i(batch, N_NODES, gr);
        int hi = lower_bound_i(batch, N_NODES, gr + 1);
        pb[w][lane] = s / fmaxf((float)(hi - lo), 1.f);
        if (lane < 32) {
            float a = b1[lane];
            #pragma unroll
            for (int cc = 0; cc < 64; ++cc) a += pb[w][cc] * w1[cc * 32 + lane];
            hb[w][lane] = fmaxf(a, 0.f);
        }
        if (lane < 16) {
            float a = b2[lane];
            #pragma unroll
            for (int j = 0; j < 32; ++j) a += hb[w][j] * w2[j * 16 + lane];
            float mx = a;
            #pragma unroll
            for (int o = 8; o; o >>= 1) mx = fmaxf(mx, __shfl_xor(mx, o, 16));
            float ex = __expf(a - mx);
            float dn = ex;
            #pragma unroll
            for (int o = 8; o; o >>= 1) dn += __shfl_xor(dn, o, 16);
            out[gr * 16 + lane] = a - (mx + logf(dn));
        }
    }
}

// ---------------- launch -----------------------------------------------------
extern "C" void kernel_launch(void* const* d_in, const int* in_sizes, int n_in,
                              void* d_out, int out_size, void* d_ws, size_t ws_size,
                              hipStream_t stream) {
    const float* x     = (const float*)d_in[0];
    const int*   ei    = (const int*)d_in[1];
    const int*   batch = (const int*)d_in[2];
    // d_in[3..6] = signal-attention MLP: softmax over size-1 axis == identity -> unused
    const float* g1_w  = (const float*)d_in[7];
    const float* g1_as = (const float*)d_in[8];
    const float* g1_ad = (const float*)d_in[9];
    const float* g1_b  = (const float*)d_in[10];
    const float* g2_w  = (const float*)d_in[11];
    const float* g2_as = (const float*)d_in[12];
    const float* g2_ad = (const float*)d_in[13];
    const float* g2_b  = (const float*)d_in[14];
    const float* cl_w1 = (const float*)d_in[15];
    const float* cl_b1 = (const float*)d_in[16];
    const float* cl_w2 = (const float*)d_in[17];
    const float* cl_b2 = (const float*)d_in[18];

    char* ws = (char*)d_ws;
    ushort_t* xb     = (ushort_t*)(ws + OFF_XB);
    uchar_t*  h1f8   = (uchar_t*)(ws + OFF_H1F8);
    ushort_t* out1b  = (ushort_t*)(ws + OFF_OUT1B);
    uchar_t*  h2f8   = (uchar_t*)(ws + OFF_H2F8);
    float*    a1s    = (float*)(ws + OFF_A1S);
    float*    a1d    = (float*)(ws + OFF_A1D);
    float*    a2s    = (float*)(ws + OFF_A2S);
    float*    a2d    = (float*)(ws + OFF_A2D);
    int*      cnt    = (int*)(ws + OFF_CNT);
    float*    slots  = (float*)(ws + OFF_SLOTS);
    int*      done   = (int*)(ws + OFF_DONE);
    int*      rowptr = (int*)(ws + OFF_ROWPTR);
    int*      cursor = (int*)(ws + OFF_CURSOR);
    int*      csr    = (int*)(ws + OFF_CSR);
    int*      part   = (int*)(ws + OFF_PART);
    ushort_t* w1t    = (ushort_t*)(ws + OFF_W1T);
    ushort_t* w2t    = (ushort_t*)(ws + OFF_W2T);

    const int npart = (N_NODES + 255) / 256;   // 196

    // single memset: cnt + slots + done contiguous
    hipMemsetAsync(cnt, 0, 200000 + N_GRAPHS * NSLOT * HID * sizeof(float) + 64, stream);

    prep_all<<<N_NODES * 256 / 4 / 256, 256, 0, stream>>>(x, xb, g1_w, g2_w, w1t, w2t, ei, cnt);

    scan_partial<<<npart, 256, 0, stream>>>(cnt, part);
    scan_final2<<<npart, 256, 0, stream>>>(cnt, part, rowptr, cursor, npart);
    scatter_kernel<<<(N_EDGES + 255) / 256, 256, 0, stream>>>(ei, cursor, csr);

    // GAT1: h1(fp8) = x @ g1_w + fused att logits (f32)
    gemm1_swz<<<2 * ((N_NODES + 127) / 128), 256, 0, stream>>>(
        xb, w1t, h1f8, N_NODES, g1_as, g1_ad, a1s, a1d);
    gat1_agg<<<N_NODES / 4, 256, 0, stream>>>(
        (const uint_t*)h1f8, a1s, a1d, rowptr, csr, g1_b, out1b);

    // GAT2: h2(fp8) = out1 @ g2_w + fused att logits; agg+pool+classifier
    gemm2_swz<<<(N_NODES + 127) / 128, 256, 0, stream>>>(
        out1b, w2t, h2f8, N_NODES, g2_as, g2_ad, a2s, a2d);
    gat2_agg_pool<<<N_NODES / 4, 256, 0, stream>>>(
        (const uint_t*)h2f8, a2s, a2d, rowptr, csr, g2_b, batch, slots, done,
        cl_w1, cl_b1, cl_w2, cl_b2, (float*)d_out);
}

// Round 12
// 223.571 us; speedup vs baseline: 6.3817x; 6.3817x over previous
//
#include <hip/hip_runtime.h>
#include <math.h>

#define N_NODES 50000
#define N_EDGES 800000
#define N_GRAPHS 128
#define IN_CH 256
#define HID 64
#define HEADS 4
#define OUT_CH 16
#define NSLOT 32

typedef unsigned short ushort_t;
typedef unsigned int uint_t;
typedef unsigned char uchar_t;
typedef __attribute__((ext_vector_type(8))) short bf16x8;
typedef __attribute__((ext_vector_type(4))) float f32x4;
typedef __attribute__((ext_vector_type(2))) float f32x2;

// ---------------- workspace layout (bytes, 64-aligned) ----------------
static const size_t OFF_XB     = 0;           // x bf16       25,600,000
static const size_t OFF_H1F8   = 25600000;    // h1 fp8       12,800,000
static const size_t OFF_OUT1B  = 38400000;    // out1 bf16    25,600,000
static const size_t OFF_H2F8   = 64000000;    // h2 fp8        3,200,000
static const size_t OFF_A1S    = 67200000;    //                 800,000
static const size_t OFF_A1D    = 68000000;    //                 800,000
static const size_t OFF_A2S    = 68800000;    //                 200,000
static const size_t OFF_A2D    = 69000000;    //                 200,000
// cnt + slots contiguous -> ONE memset
static const size_t OFF_CNT    = 69200000;    //                 200,000
static const size_t OFF_SLOTS  = 69400000;    //               1,048,576
static const size_t OFF_ROWPTR = 70448640;    //                 200,064
static const size_t OFF_CURSOR = 70648704;    //                 200,000
static const size_t OFF_CSR    = 70848704;    //               3,200,000
static const size_t OFF_PART   = 74048704;    //                   1,024
static const size_t OFF_W1T    = 74049728;    //                 131,072
static const size_t OFF_W2T    = 74180800;    //                  32,768

#define DEV static __device__ __forceinline__

DEV float leaky02(float v) { return v > 0.f ? v : 0.2f * v; }
DEV float bf2f(ushort_t s) { return __uint_as_float(((uint_t)s) << 16); }
DEV ushort_t f2bf(float f) {
    uint_t u = __float_as_uint(f);
    return (ushort_t)((u + 0x7FFFu + ((u >> 16) & 1u)) >> 16);
}
DEV uchar_t f2fp8(float f) {
    int p = __builtin_amdgcn_cvt_pk_fp8_f32(f, 0.f, 0, false);
    return (uchar_t)(p & 0xFF);
}
DEV void dec16(uint4 v, float* o) {
    f32x2 t;
    t = __builtin_amdgcn_cvt_pk_f32_fp8(v.x, false); o[0]  = t[0]; o[1]  = t[1];
    t = __builtin_amdgcn_cvt_pk_f32_fp8(v.x, true);  o[2]  = t[0]; o[3]  = t[1];
    t = __builtin_amdgcn_cvt_pk_f32_fp8(v.y, false); o[4]  = t[0]; o[5]  = t[1];
    t = __builtin_amdgcn_cvt_pk_f32_fp8(v.y, true);  o[6]  = t[0]; o[7]  = t[1];
    t = __builtin_amdgcn_cvt_pk_f32_fp8(v.z, false); o[8]  = t[0]; o[9]  = t[1];
    t = __builtin_amdgcn_cvt_pk_f32_fp8(v.z, true);  o[10] = t[0]; o[11] = t[1];
    t = __builtin_amdgcn_cvt_pk_f32_fp8(v.w, false); o[12] = t[0]; o[13] = t[1];
    t = __builtin_amdgcn_cvt_pk_f32_fp8(v.w, true);  o[14] = t[0]; o[15] = t[1];
}
DEV int wred_sum_i(int v) {
    #pragma unroll
    for (int o = 32; o; o >>= 1) v += __shfl_xor(v, o, 64);
    return v;
}
DEV int lower_bound_i(const int* a, int n, int key) {
    int lo = 0, hi = n;
    while (lo < hi) { int mid = (lo + hi) >> 1; if (a[mid] < key) lo = mid + 1; else hi = mid; }
    return lo;
}
DEV void gload_lds16(const void* g, void* l) {
    __builtin_amdgcn_global_load_lds(
        (const __attribute__((address_space(1))) uint_t*)g,
        (__attribute__((address_space(3))) uint_t*)l, 16, 0, 0);
}

// ---------------- fused prep: x->bf16, weights->bf16^T, degree count --------
__global__ void prep_all(const float* __restrict__ x, ushort_t* __restrict__ xb,
                         const float* __restrict__ g1w, const float* __restrict__ g2w,
                         ushort_t* __restrict__ w1t, ushort_t* __restrict__ w2t,
                         const int* __restrict__ ei, int* __restrict__ cnt) {
    int tid = blockIdx.x * 256 + threadIdx.x;     // 3,200,000 threads
    {   // convert x, one float4 per thread
        float4 v = *reinterpret_cast<const float4*>(&x[(size_t)tid * 4]);
        ushort4 o;
        o.x = f2bf(v.x); o.y = f2bf(v.y); o.z = f2bf(v.z); o.w = f2bf(v.w);
        *reinterpret_cast<ushort4*>(&xb[(size_t)tid * 4]) = o;
    }
    if (tid < N_EDGES) atomicAdd(&cnt[ei[N_EDGES + tid]], 1);
    if (tid < 256 * 256) {                        // w1t[n][k] = g1w[k][n]
        int n = tid >> 8, k = tid & 255;
        w1t[tid] = f2bf(g1w[k * 256 + n]);
    }
    if (tid < 64 * 256) {                         // w2t[n][k] = g2w[k][n]
        int n = tid >> 8, k = tid & 255;
        w2t[tid] = f2bf(g2w[k * 64 + n]);
    }
}

// ---------------- CSR build: 2-kernel scan ----------------------------------
__global__ void scan_partial(const int* __restrict__ cnt, int* __restrict__ part) {
    __shared__ int wsum[4];
    int i = blockIdx.x * 256 + threadIdx.x;
    int v = (i < N_NODES) ? cnt[i] : 0;
    v = wred_sum_i(v);
    if ((threadIdx.x & 63) == 0) wsum[threadIdx.x >> 6] = v;
    __syncthreads();
    if (threadIdx.x == 0) part[blockIdx.x] = wsum[0] + wsum[1] + wsum[2] + wsum[3];
}

__global__ void scan_final2(const int* __restrict__ cnt, const int* __restrict__ part,
                            int* __restrict__ rowptr, int* __restrict__ cursor, int npart) {
    __shared__ int buf[256];
    __shared__ int ws4[4];
    int b = blockIdx.x, tid = threadIdx.x;
    int pv = (tid < b && tid < npart) ? part[tid] : 0;
    pv = wred_sum_i(pv);
    if ((tid & 63) == 0) ws4[tid >> 6] = pv;
    __syncthreads();
    int base = ws4[0] + ws4[1] + ws4[2] + ws4[3];
    int i = b * 256 + tid;
    int v = (i < N_NODES) ? cnt[i] : 0;
    buf[tid] = v; __syncthreads();
    for (int off = 1; off < 256; off <<= 1) {
        int t = (tid >= off) ? buf[tid - off] : 0;
        __syncthreads();
        buf[tid] += t;
        __syncthreads();
    }
    if (i < N_NODES) {
        int incl = buf[tid] + base;
        rowptr[i + 1] = incl;
        cursor[i] = incl - v;
    }
    if (i == 0) rowptr[0] = 0;
}

__global__ void scatter_kernel(const int* __restrict__ ei, int* __restrict__ cursor,
                               int* __restrict__ csr) {
    int e = blockIdx.x * blockDim.x + threadIdx.x;
    if (e < N_EDGES) {
        int d = ei[N_EDGES + e];
        int pos = atomicAdd(&cursor[d], 1);
        csr[pos] = ei[e];
    }
}

// ---------------- GEMM1: 128x128 tile, swizzled LDS, fp8 C, fused logits ----
__global__ __launch_bounds__(256) void gemm1_swz(
    const ushort_t* __restrict__ A, const ushort_t* __restrict__ Bt,
    uchar_t* __restrict__ C8, int M,
    const float* __restrict__ att_src, const float* __restrict__ att_dst,
    float* __restrict__ as_out, float* __restrict__ ad_out) {
    __shared__ ushort_t As[128 * 64];
    __shared__ ushort_t Bs[128 * 64];
    const int tid = threadIdx.x;
    const int w = tid >> 6, lane = tid & 63;
    const int lr = lane & 15, lg = lane >> 4;
    const int m0 = (blockIdx.x >> 1) * 128, n0 = (blockIdx.x & 1) * 128;
    const int wm = (w >> 1) * 64, wn = (w & 1) * 64;
    f32x4 acc[4][4];
    #pragma unroll
    for (int i = 0; i < 4; ++i)
        #pragma unroll
        for (int j = 0; j < 4; ++j) acc[i][j] = (f32x4){0.f, 0.f, 0.f, 0.f};

    const int rsub = lane >> 3;
    const int gc = (lane & 7) ^ rsub;

    for (int k0 = 0; k0 < 256; k0 += 64) {
        #pragma unroll
        for (int t = 0; t < 4; ++t) {
            int slot = t * 4 + w;
            int row = slot * 8 + rsub;
            int gm = m0 + row; if (gm > M - 1) gm = M - 1;
            gload_lds16((const char*)A + (size_t)gm * 512 + k0 * 2 + gc * 16,
                        (char*)As + slot * 1024);
        }
        #pragma unroll
        for (int t = 0; t < 4; ++t) {
            int slot = t * 4 + w;
            int row = slot * 8 + rsub;
            gload_lds16((const char*)Bt + (size_t)(n0 + row) * 512 + k0 * 2 + gc * 16,
                        (char*)Bs + slot * 1024);
        }
        __syncthreads();
        #pragma unroll
        for (int kk = 0; kk < 2; ++kk) {
            const int chunk = kk * 4 + lg;
            bf16x8 av[4], bv[4];
            #pragma unroll
            for (int mf = 0; mf < 4; ++mf) {
                int row = wm + mf * 16 + lr;
                av[mf] = *reinterpret_cast<const bf16x8*>(&As[row * 64 + ((chunk ^ (row & 7)) * 8)]);
            }
            #pragma unroll
            for (int nf = 0; nf < 4; ++nf) {
                int row = wn + nf * 16 + lr;
                bv[nf] = *reinterpret_cast<const bf16x8*>(&Bs[row * 64 + ((chunk ^ (row & 7)) * 8)]);
            }
            #pragma unroll
            for (int mf = 0; mf < 4; ++mf)
                #pragma unroll
                for (int nf = 0; nf < 4; ++nf)
                    acc[mf][nf] = __builtin_amdgcn_mfma_f32_16x16x32_bf16(av[mf], bv[nf], acc[mf][nf], 0, 0, 0);
        }
        __syncthreads();
    }
    #pragma unroll
    for (int mf = 0; mf < 4; ++mf)
        #pragma unroll
        for (int nf = 0; nf < 4; ++nf)
            #pragma unroll
            for (int r = 0; r < 4; ++r) {
                int row = m0 + wm + mf * 16 + lg * 4 + r;
                int col = n0 + wn + nf * 16 + lr;
                if (row < M) C8[(size_t)row * 256 + col] = f2fp8(acc[mf][nf][r]);
            }
    {   // fused att logits (head = 64-col slice, wave-exclusive), full precision
        float asr[4], adr[4];
        #pragma unroll
        for (int nf = 0; nf < 4; ++nf) {
            int col = n0 + wn + nf * 16 + lr;
            asr[nf] = att_src[col];
            adr[nf] = att_dst[col];
        }
        const int hidx = (n0 + wn) >> 6;
        #pragma unroll
        for (int mf = 0; mf < 4; ++mf)
            #pragma unroll
            for (int r = 0; r < 4; ++r) {
                float s = 0.f, d = 0.f;
                #pragma unroll
                for (int nf = 0; nf < 4; ++nf) {
                    float v = acc[mf][nf][r];
                    s += v * asr[nf]; d += v * adr[nf];
                }
                #pragma unroll
                for (int o = 8; o; o >>= 1) {
                    s += __shfl_xor(s, o, 64);
                    d += __shfl_xor(d, o, 64);
                }
                int row = m0 + wm + mf * 16 + lg * 4 + r;
                if (lr == 0 && row < M) {
                    as_out[row * 4 + hidx] = s;
                    ad_out[row * 4 + hidx] = d;
                }
            }
    }
}

// ---------------- GEMM2 (BN=64), fp8 C, fused att logits --------------------
__global__ __launch_bounds__(256) void gemm2_swz(
    const ushort_t* __restrict__ A, const ushort_t* __restrict__ Bt,
    uchar_t* __restrict__ C8, int M,
    const float* __restrict__ att_src, const float* __restrict__ att_dst,
    float* __restrict__ as_out, float* __restrict__ ad_out) {
    __shared__ ushort_t As[128 * 64];
    __shared__ ushort_t Bs[64 * 64];
    const int tid = threadIdx.x;
    const int w = tid >> 6, lane = tid & 63;
    const int lr = lane & 15, lg = lane >> 4;
    const int m0 = blockIdx.x * 128;
    const int wm = w * 32;
    f32x4 acc[2][4];
    #pragma unroll
    for (int i = 0; i < 2; ++i)
        #pragma unroll
        for (int j = 0; j < 4; ++j) acc[i][j] = (f32x4){0.f, 0.f, 0.f, 0.f};

    const int rsub = lane >> 3;
    const int gc = (lane & 7) ^ rsub;

    for (int k0 = 0; k0 < 256; k0 += 64) {
        #pragma unroll
        for (int t = 0; t < 4; ++t) {
            int slot = t * 4 + w;
            int row = slot * 8 + rsub;
            int gm = m0 + row; if (gm > M - 1) gm = M - 1;
            gload_lds16((const char*)A + (size_t)gm * 512 + k0 * 2 + gc * 16,
                        (char*)As + slot * 1024);
        }
        #pragma unroll
        for (int t = 0; t < 2; ++t) {
            int slot = t * 4 + w;
            int row = slot * 8 + rsub;
            gload_lds16((const char*)Bt + (size_t)row * 512 + k0 * 2 + gc * 16,
                        (char*)Bs + slot * 1024);
        }
        __syncthreads();
        #pragma unroll
        for (int kk = 0; kk < 2; ++kk) {
            const int chunk = kk * 4 + lg;
            bf16x8 av[2], bv[4];
            #pragma unroll
            for (int mf = 0; mf < 2; ++mf) {
                int row = wm + mf * 16 + lr;
                av[mf] = *reinterpret_cast<const bf16x8*>(&As[row * 64 + ((chunk ^ (row & 7)) * 8)]);
            }
            #pragma unroll
            for (int nf = 0; nf < 4; ++nf) {
                int row = nf * 16 + lr;
                bv[nf] = *reinterpret_cast<const bf16x8*>(&Bs[row * 64 + ((chunk ^ (row & 7)) * 8)]);
            }
            #pragma unroll
            for (int mf = 0; mf < 2; ++mf)
                #pragma unroll
                for (int nf = 0; nf < 4; ++nf)
                    acc[mf][nf] = __builtin_amdgcn_mfma_f32_16x16x32_bf16(av[mf], bv[nf], acc[mf][nf], 0, 0, 0);
        }
        __syncthreads();
    }
    #pragma unroll
    for (int mf = 0; mf < 2; ++mf)
        #pragma unroll
        for (int nf = 0; nf < 4; ++nf)
            #pragma unroll
            for (int r = 0; r < 4; ++r) {
                int row = m0 + wm + mf * 16 + lg * 4 + r;
                int col = nf * 16 + lr;
                if (row < M) C8[(size_t)row * 64 + col] = f2fp8(acc[mf][nf][r]);
            }
    {
        float asr[4], adr[4];
        #pragma unroll
        for (int nf = 0; nf < 4; ++nf) {
            asr[nf] = att_src[nf * 16 + lr];
            adr[nf] = att_dst[nf * 16 + lr];
        }
        #pragma unroll
        for (int mf = 0; mf < 2; ++mf)
            #pragma unroll
            for (int r = 0; r < 4; ++r) {
                float s = 0.f, d = 0.f;
                #pragma unroll
                for (int nf = 0; nf < 4; ++nf) {
                    float v = acc[mf][nf][r];
                    s += v * asr[nf]; d += v * adr[nf];
                }
                #pragma unroll
                for (int o = 8; o; o >>= 1) {
                    s += __shfl_xor(s, o, 64);
                    d += __shfl_xor(d, o, 64);
                }
                int row = m0 + wm + mf * 16 + lg * 4 + r;
                if (lr == 0 && row < M) { as_out[row] = s; ad_out[row] = d; }
            }
    }
}

// ---------------- GAT1: 4-edge groups x 16 lanes x uint4 (16ch/lane) --------
__global__ void gat1_agg(const uint_t* __restrict__ h1u, const float* __restrict__ a1s,
                         const float* __restrict__ a1d, const int* __restrict__ rowptr,
                         const int* __restrict__ csr, const float* __restrict__ bias,
                         ushort_t* __restrict__ out1b) {
    const uint4* h1q = (const uint4*)h1u;
    int w = threadIdx.x >> 6;
    int i = blockIdx.x * 4 + w;                // N_NODES = 4*12500 exactly
    int lane = threadIdx.x & 63;
    int g = lane >> 4, j16 = lane & 15;
    int hd = j16 >> 2;
    int beg = rowptr[i], end = rowptr[i + 1];
    float ad = a1d[i * 4 + hd];
    float acc[16];
    float den = 0.f;
    #pragma unroll
    for (int k = 0; k < 16; ++k) acc[k] = 0.f;
    if (g == 0) {   // self loop counted once
        float p = __expf(leaky02(a1s[i * 4 + hd] + ad));
        float hv[16];
        dec16(h1q[(uint_t)i * 16 + j16], hv);
        den = p;
        #pragma unroll
        for (int k = 0; k < 16; ++k) acc[k] = p * hv[k];
    }
    for (int e = beg; e < end; e += 16) {
        int s[4]; float q[4]; uint4 v[4];
        #pragma unroll
        for (int jj = 0; jj < 4; ++jj) {
            int idx = e + jj * 4 + g;
            s[jj] = (idx < end) ? csr[idx] : i;
        }
        #pragma unroll
        for (int jj = 0; jj < 4; ++jj)
            v[jj] = h1q[(uint_t)s[jj] * 16 + j16];      // issue gathers early
        #pragma unroll
        for (int jj = 0; jj < 4; ++jj) {
            int idx = e + jj * 4 + g;
            q[jj] = (idx < end) ? __expf(leaky02(a1s[(uint_t)s[jj] * 4 + hd] + ad)) : 0.f;
        }
        #pragma unroll
        for (int jj = 0; jj < 4; ++jj) {
            float hv[16];
            dec16(v[jj], hv);
            den += q[jj];
            #pragma unroll
            for (int k = 0; k < 16; ++k) acc[k] += q[jj] * hv[k];
        }
    }
    den += __shfl_xor(den, 16, 64); den += __shfl_xor(den, 32, 64);
    #pragma unroll
    for (int k = 0; k < 16; ++k) {
        acc[k] += __shfl_xor(acc[k], 16, 64);
        acc[k] += __shfl_xor(acc[k], 32, 64);
    }
    if (g == 0) {
        float inv = 1.f / (den + 1e-16f);
        ushort_t tmp[16];
        #pragma unroll
        for (int k4 = 0; k4 < 4; ++k4) {
            float4 bv = *reinterpret_cast<const float4*>(&bias[j16 * 16 + k4 * 4]);
            tmp[k4 * 4 + 0] = f2bf(fmaxf(acc[k4 * 4 + 0] * inv + bv.x, 0.f));
            tmp[k4 * 4 + 1] = f2bf(fmaxf(acc[k4 * 4 + 1] * inv + bv.y, 0.f));
            tmp[k4 * 4 + 2] = f2bf(fmaxf(acc[k4 * 4 + 2] * inv + bv.z, 0.f));
            tmp[k4 * 4 + 3] = f2bf(fmaxf(acc[k4 * 4 + 3] * inv + bv.w, 0.f));
        }
        *reinterpret_cast<uint4*>(&out1b[(size_t)i * 256 + j16 * 16])     = *reinterpret_cast<uint4*>(&tmp[0]);
        *reinterpret_cast<uint4*>(&out1b[(size_t)i * 256 + j16 * 16 + 8]) = *reinterpret_cast<uint4*>(&tmp[8]);
    }
}

// ---------------- GAT2 + pool: fp8 gather + block-level LDS pool reduce -----
__global__ void gat2_agg_pool(const uint_t* __restrict__ h2u, const float* __restrict__ a2s,
                              const float* __restrict__ a2d, const int* __restrict__ rowptr,
                              const int* __restrict__ csr, const float* __restrict__ bias,
                              const int* __restrict__ batch, float* __restrict__ slots) {
    __shared__ float fv[4][64];
    __shared__ int bg[4];
    int w = threadIdx.x >> 6;
    int i = blockIdx.x * 4 + w;                // N_NODES = 4*12500 exactly
    int lane = threadIdx.x & 63;
    int g = lane >> 4, c = lane & 15;
    int beg = rowptr[i], end = rowptr[i + 1];
    float ad = a2d[i];
    float acc0 = 0.f, acc1 = 0.f, acc2 = 0.f, acc3 = 0.f, qsum = 0.f;
    if (g == 0) {   // self loop counted once
        float p = __expf(leaky02(a2s[i] + ad));
        uint_t v = h2u[(size_t)i * 16 + c];
        f32x2 lo = __builtin_amdgcn_cvt_pk_f32_fp8(v, false);
        f32x2 hi = __builtin_amdgcn_cvt_pk_f32_fp8(v, true);
        qsum = p;
        acc0 = p * lo[0]; acc1 = p * lo[1]; acc2 = p * hi[0]; acc3 = p * hi[1];
    }
    for (int e = beg; e < end; e += 16) {
        int  s[4]; float q[4]; uint_t hv[4];
        #pragma unroll
        for (int j = 0; j < 4; ++j) {
            int idx = e + j * 4 + g;
            s[j] = (idx < end) ? csr[idx] : i;
        }
        #pragma unroll
        for (int j = 0; j < 4; ++j) hv[j] = h2u[(size_t)s[j] * 16 + c];
        #pragma unroll
        for (int j = 0; j < 4; ++j) {
            int idx = e + j * 4 + g;
            q[j] = (idx < end) ? __expf(leaky02(a2s[s[j]] + ad)) : 0.f;
        }
        #pragma unroll
        for (int j = 0; j < 4; ++j) {
            f32x2 lo = __builtin_amdgcn_cvt_pk_f32_fp8(hv[j], false);
            f32x2 hi = __builtin_amdgcn_cvt_pk_f32_fp8(hv[j], true);
            qsum += q[j];
            acc0 += q[j] * lo[0]; acc1 += q[j] * lo[1];
            acc2 += q[j] * hi[0]; acc3 += q[j] * hi[1];
        }
    }
    qsum += __shfl_xor(qsum, 16, 64); qsum += __shfl_xor(qsum, 32, 64);
    acc0 += __shfl_xor(acc0, 16, 64); acc0 += __shfl_xor(acc0, 32, 64);
    acc1 += __shfl_xor(acc1, 16, 64); acc1 += __shfl_xor(acc1, 32, 64);
    acc2 += __shfl_xor(acc2, 16, 64); acc2 += __shfl_xor(acc2, 32, 64);
    acc3 += __shfl_xor(acc3, 16, 64); acc3 += __shfl_xor(acc3, 32, 64);
    if (g == 0) {
        float inv = 1.f / (qsum + 1e-16f);
        fv[w][c * 4 + 0] = fmaxf(acc0 * inv + bias[c * 4 + 0], 0.f);
        fv[w][c * 4 + 1] = fmaxf(acc1 * inv + bias[c * 4 + 1], 0.f);
        fv[w][c * 4 + 2] = fmaxf(acc2 * inv + bias[c * 4 + 2], 0.f);
        fv[w][c * 4 + 3] = fmaxf(acc3 * inv + bias[c * 4 + 3], 0.f);
        if (c == 0) bg[w] = batch[i];
    }
    __syncthreads();
    if (w == 0) {
        int slot = blockIdx.x & (NSLOT - 1);
        int g0 = bg[0];
        float s = 0.f;
        #pragma unroll
        for (int r = 0; r < 4; ++r) if (bg[r] == g0) s += fv[r][lane];
        atomicAdd(&slots[((size_t)g0 * NSLOT + slot) * 64 + lane], s);
        #pragma unroll
        for (int r = 1; r < 4; ++r)
            if (bg[r] != g0)
                atomicAdd(&slots[((size_t)bg[r] * NSLOT + slot) * 64 + lane], fv[r][lane]);
    }
}

// ---------------- slot-reduce + classifier (one block per graph) -----------
__global__ void cls_kernel(const float* __restrict__ slots, const int* __restrict__ batch,
                           const float* __restrict__ w1, const float* __restrict__ b1,
                           const float* __restrict__ w2, const float* __restrict__ b2,
                           float* __restrict__ out) {
    int g = blockIdx.x;
    int t = threadIdx.x;   // 64
    __shared__ float p[64];
    __shared__ float hbuf[32];
    float s = 0.f;
    #pragma unroll
    for (int sl = 0; sl < NSLOT; ++sl) s += slots[((size_t)g * NSLOT + sl) * 64 + t];
    int lo = lower_bound_i(batch, N_NODES, g);
    int hi = lower_bound_i(batch, N_NODES, g + 1);
    p[t] = s / fmaxf((float)(hi - lo), 1.f);
    __syncthreads();
    if (t < 32) {
        float a = b1[t];
        #pragma unroll
        for (int c = 0; c < 64; ++c) a += p[c] * w1[c * 32 + t];
        hbuf[t] = fmaxf(a, 0.f);
    }
    __syncthreads();
    if (t == 0) {
        float logit[16];
        float mx = -INFINITY;
        #pragma unroll
        for (int o = 0; o < 16; ++o) {
            float a = b2[o];
            #pragma unroll
            for (int j = 0; j < 32; ++j) a += hbuf[j] * w2[j * 16 + o];
            logit[o] = a;
            mx = fmaxf(mx, a);
        }
        float den = 0.f;
        #pragma unroll
        for (int o = 0; o < 16; ++o) den += __expf(logit[o] - mx);
        float lse = mx + logf(den);
        #pragma unroll
        for (int o = 0; o < 16; ++o) out[g * 16 + o] = logit[o] - lse;
    }
}

// ---------------- launch -----------------------------------------------------
extern "C" void kernel_launch(void* const* d_in, const int* in_sizes, int n_in,
                              void* d_out, int out_size, void* d_ws, size_t ws_size,
                              hipStream_t stream) {
    const float* x     = (const float*)d_in[0];
    const int*   ei    = (const int*)d_in[1];
    const int*   batch = (const int*)d_in[2];
    // d_in[3..6] = signal-attention MLP: softmax over size-1 axis == identity -> unused
    const float* g1_w  = (const float*)d_in[7];
    const float* g1_as = (const float*)d_in[8];
    const float* g1_ad = (const float*)d_in[9];
    const float* g1_b  = (const float*)d_in[10];
    const float* g2_w  = (const float*)d_in[11];
    const float* g2_as = (const float*)d_in[12];
    const float* g2_ad = (const float*)d_in[13];
    const float* g2_b  = (const float*)d_in[14];
    const float* cl_w1 = (const float*)d_in[15];
    const float* cl_b1 = (const float*)d_in[16];
    const float* cl_w2 = (const float*)d_in[17];
    const float* cl_b2 = (const float*)d_in[18];

    char* ws = (char*)d_ws;
    ushort_t* xb     = (ushort_t*)(ws + OFF_XB);
    uchar_t*  h1f8   = (uchar_t*)(ws + OFF_H1F8);
    ushort_t* out1b  = (ushort_t*)(ws + OFF_OUT1B);
    uchar_t*  h2f8   = (uchar_t*)(ws + OFF_H2F8);
    float*    a1s    = (float*)(ws + OFF_A1S);
    float*    a1d    = (float*)(ws + OFF_A1D);
    float*    a2s    = (float*)(ws + OFF_A2S);
    float*    a2d    = (float*)(ws + OFF_A2D);
    int*      cnt    = (int*)(ws + OFF_CNT);
    float*    slots  = (float*)(ws + OFF_SLOTS);
    int*      rowptr = (int*)(ws + OFF_ROWPTR);
    int*      cursor = (int*)(ws + OFF_CURSOR);
    int*      csr    = (int*)(ws + OFF_CSR);
    int*      part   = (int*)(ws + OFF_PART);
    ushort_t* w1t    = (ushort_t*)(ws + OFF_W1T);
    ushort_t* w2t    = (ushort_t*)(ws + OFF_W2T);

    const int npart = (N_NODES + 255) / 256;   // 196

    // single memset: cnt + slots contiguous
    hipMemsetAsync(cnt, 0, 200000 + N_GRAPHS * NSLOT * HID * sizeof(float), stream);

    prep_all<<<N_NODES * 256 / 4 / 256, 256, 0, stream>>>(x, xb, g1_w, g2_w, w1t, w2t, ei, cnt);

    scan_partial<<<npart, 256, 0, stream>>>(cnt, part);
    scan_final2<<<npart, 256, 0, stream>>>(cnt, part, rowptr, cursor, npart);
    scatter_kernel<<<(N_EDGES + 255) / 256, 256, 0, stream>>>(ei, cursor, csr);

    // GAT1: h1(fp8) = x @ g1_w + fused att logits (f32)
    gemm1_swz<<<2 * ((N_NODES + 127) / 128), 256, 0, stream>>>(
        xb, w1t, h1f8, N_NODES, g1_as, g1_ad, a1s, a1d);
    gat1_agg<<<N_NODES / 4, 256, 0, stream>>>(
        (const uint_t*)h1f8, a1s, a1d, rowptr, csr, g1_b, out1b);

    // GAT2: h2(fp8) = out1 @ g2_w + fused att logits; agg+pool
    gemm2_swz<<<(N_NODES + 127) / 128, 256, 0, stream>>>(
        out1b, w2t, h2f8, N_NODES, g2_as, g2_ad, a2s, a2d);
    gat2_agg_pool<<<N_NODES / 4, 256, 0, stream>>>(
        (const uint_t*)h2f8, a2s, a2d, rowptr, csr, g2_b, batch, slots);

    cls_kernel<<<N_GRAPHS, 64, 0, stream>>>(slots, batch, cl_w1, cl_b1, cl_w2, cl_b2, (float*)d_out);
}

// Round 13
// 216.523 us; speedup vs baseline: 6.5894x; 1.0326x over previous
//
#include <hip/hip_runtime.h>
#include <math.h>

#define N_NODES 50000
#define N_EDGES 800000
#define N_GRAPHS 128
#define IN_CH 256
#define HID 64
#define HEADS 4
#define OUT_CH 16
#define NSLOT 32

typedef unsigned short ushort_t;
typedef unsigned int uint_t;
typedef unsigned char uchar_t;
typedef __attribute__((ext_vector_type(8))) short bf16x8;
typedef __attribute__((ext_vector_type(4))) float f32x4;
typedef __attribute__((ext_vector_type(2))) float f32x2;

// ---------------- workspace layout (bytes, 64-aligned) ----------------
static const size_t OFF_XB     = 0;           // x bf16       25,600,000
static const size_t OFF_H1F8   = 25600000;    // h1 fp8       12,800,000
static const size_t OFF_OUT1B  = 38400000;    // out1 bf16    25,600,000
static const size_t OFF_H2F8   = 64000000;    // h2 fp8        3,200,000
static const size_t OFF_A1S    = 67200000;    //                 800,000
static const size_t OFF_A1D    = 68000000;    //                 800,000
static const size_t OFF_A2S    = 68800000;    //                 200,000
static const size_t OFF_A2D    = 69000000;    //                 200,000
// cnt + slots contiguous -> ONE memset
static const size_t OFF_CNT    = 69200000;    //                 200,000
static const size_t OFF_SLOTS  = 69400000;    //               1,048,576
static const size_t OFF_ROWPTR = 70448640;    //                 200,064
static const size_t OFF_CURSOR = 70648704;    //                 200,000
static const size_t OFF_CSR    = 70848704;    //               3,200,000
static const size_t OFF_PART   = 74048704;    //                   1,024
static const size_t OFF_W1T    = 74049728;    //                 131,072
static const size_t OFF_W2T    = 74180800;    //                  32,768

#define DEV static __device__ __forceinline__

DEV float leaky02(float v) { return v > 0.f ? v : 0.2f * v; }
DEV float bf2f(ushort_t s) { return __uint_as_float(((uint_t)s) << 16); }
DEV ushort_t f2bf(float f) {
    uint_t u = __float_as_uint(f);
    return (ushort_t)((u + 0x7FFFu + ((u >> 16) & 1u)) >> 16);
}
DEV uchar_t f2fp8(float f) {
    int p = __builtin_amdgcn_cvt_pk_fp8_f32(f, 0.f, 0, false);
    return (uchar_t)(p & 0xFF);
}
DEV int wred_sum_i(int v) {
    #pragma unroll
    for (int o = 32; o; o >>= 1) v += __shfl_xor(v, o, 64);
    return v;
}
DEV int lower_bound_i(const int* a, int n, int key) {
    int lo = 0, hi = n;
    while (lo < hi) { int mid = (lo + hi) >> 1; if (a[mid] < key) lo = mid + 1; else hi = mid; }
    return lo;
}
DEV void gload_lds16(const void* g, void* l) {
    __builtin_amdgcn_global_load_lds(
        (const __attribute__((address_space(1))) uint_t*)g,
        (__attribute__((address_space(3))) uint_t*)l, 16, 0, 0);
}

// ---------------- fused prep: x->bf16, weights->bf16^T, degree count --------
__global__ void prep_all(const float* __restrict__ x, ushort_t* __restrict__ xb,
                         const float* __restrict__ g1w, const float* __restrict__ g2w,
                         ushort_t* __restrict__ w1t, ushort_t* __restrict__ w2t,
                         const int* __restrict__ ei, int* __restrict__ cnt) {
    int tid = blockIdx.x * 256 + threadIdx.x;     // 3,200,000 threads
    {   // convert x, one float4 per thread
        float4 v = *reinterpret_cast<const float4*>(&x[(size_t)tid * 4]);
        ushort4 o;
        o.x = f2bf(v.x); o.y = f2bf(v.y); o.z = f2bf(v.z); o.w = f2bf(v.w);
        *reinterpret_cast<ushort4*>(&xb[(size_t)tid * 4]) = o;
    }
    if (tid < N_EDGES) atomicAdd(&cnt[ei[N_EDGES + tid]], 1);
    if (tid < 256 * 256) {                        // w1t[n][k] = g1w[k][n]
        int n = tid >> 8, k = tid & 255;
        w1t[tid] = f2bf(g1w[k * 256 + n]);
    }
    if (tid < 64 * 256) {                         // w2t[n][k] = g2w[k][n]
        int n = tid >> 8, k = tid & 255;
        w2t[tid] = f2bf(g2w[k * 64 + n]);
    }
}

// ---------------- CSR build: 2-kernel scan ----------------------------------
__global__ void scan_partial(const int* __restrict__ cnt, int* __restrict__ part) {
    __shared__ int wsum[4];
    int i = blockIdx.x * 256 + threadIdx.x;
    int v = (i < N_NODES) ? cnt[i] : 0;
    v = wred_sum_i(v);
    if ((threadIdx.x & 63) == 0) wsum[threadIdx.x >> 6] = v;
    __syncthreads();
    if (threadIdx.x == 0) part[blockIdx.x] = wsum[0] + wsum[1] + wsum[2] + wsum[3];
}

__global__ void scan_final2(const int* __restrict__ cnt, const int* __restrict__ part,
                            int* __restrict__ rowptr, int* __restrict__ cursor, int npart) {
    __shared__ int buf[256];
    __shared__ int ws4[4];
    int b = blockIdx.x, tid = threadIdx.x;
    int pv = (tid < b && tid < npart) ? part[tid] : 0;
    pv = wred_sum_i(pv);
    if ((tid & 63) == 0) ws4[tid >> 6] = pv;
    __syncthreads();
    int base = ws4[0] + ws4[1] + ws4[2] + ws4[3];
    int i = b * 256 + tid;
    int v = (i < N_NODES) ? cnt[i] : 0;
    buf[tid] = v; __syncthreads();
    for (int off = 1; off < 256; off <<= 1) {
        int t = (tid >= off) ? buf[tid - off] : 0;
        __syncthreads();
        buf[tid] += t;
        __syncthreads();
    }
    if (i < N_NODES) {
        int incl = buf[tid] + base;
        rowptr[i + 1] = incl;
        cursor[i] = incl - v;
    }
    if (i == 0) rowptr[0] = 0;
}

__global__ void scatter_kernel(const int* __restrict__ ei, int* __restrict__ cursor,
                               int* __restrict__ csr) {
    int e = blockIdx.x * blockDim.x + threadIdx.x;
    if (e < N_EDGES) {
        int d = ei[N_EDGES + e];
        int pos = atomicAdd(&cursor[d], 1);
        csr[pos] = ei[e];
    }
}

// ---------------- GEMM1: 128x128 tile, swizzled LDS, fp8 C, fused logits ----
__global__ __launch_bounds__(256) void gemm1_swz(
    const ushort_t* __restrict__ A, const ushort_t* __restrict__ Bt,
    uchar_t* __restrict__ C8, int M,
    const float* __restrict__ att_src, const float* __restrict__ att_dst,
    float* __restrict__ as_out, float* __restrict__ ad_out) {
    __shared__ ushort_t As[128 * 64];
    __shared__ ushort_t Bs[128 * 64];
    const int tid = threadIdx.x;
    const int w = tid >> 6, lane = tid & 63;
    const int lr = lane & 15, lg = lane >> 4;
    const int m0 = (blockIdx.x >> 1) * 128, n0 = (blockIdx.x & 1) * 128;
    const int wm = (w >> 1) * 64, wn = (w & 1) * 64;
    f32x4 acc[4][4];
    #pragma unroll
    for (int i = 0; i < 4; ++i)
        #pragma unroll
        for (int j = 0; j < 4; ++j) acc[i][j] = (f32x4){0.f, 0.f, 0.f, 0.f};

    const int rsub = lane >> 3;
    const int gc = (lane & 7) ^ rsub;

    for (int k0 = 0; k0 < 256; k0 += 64) {
        #pragma unroll
        for (int t = 0; t < 4; ++t) {
            int slot = t * 4 + w;
            int row = slot * 8 + rsub;
            int gm = m0 + row; if (gm > M - 1) gm = M - 1;
            gload_lds16((const char*)A + (size_t)gm * 512 + k0 * 2 + gc * 16,
                        (char*)As + slot * 1024);
        }
        #pragma unroll
        for (int t = 0; t < 4; ++t) {
            int slot = t * 4 + w;
            int row = slot * 8 + rsub;
            gload_lds16((const char*)Bt + (size_t)(n0 + row) * 512 + k0 * 2 + gc * 16,
                        (char*)Bs + slot * 1024);
        }
        __syncthreads();
        #pragma unroll
        for (int kk = 0; kk < 2; ++kk) {
            const int chunk = kk * 4 + lg;
            bf16x8 av[4], bv[4];
            #pragma unroll
            for (int mf = 0; mf < 4; ++mf) {
                int row = wm + mf * 16 + lr;
                av[mf] = *reinterpret_cast<const bf16x8*>(&As[row * 64 + ((chunk ^ (row & 7)) * 8)]);
            }
            #pragma unroll
            for (int nf = 0; nf < 4; ++nf) {
                int row = wn + nf * 16 + lr;
                bv[nf] = *reinterpret_cast<const bf16x8*>(&Bs[row * 64 + ((chunk ^ (row & 7)) * 8)]);
            }
            #pragma unroll
            for (int mf = 0; mf < 4; ++mf)
                #pragma unroll
                for (int nf = 0; nf < 4; ++nf)
                    acc[mf][nf] = __builtin_amdgcn_mfma_f32_16x16x32_bf16(av[mf], bv[nf], acc[mf][nf], 0, 0, 0);
        }
        __syncthreads();
    }
    #pragma unroll
    for (int mf = 0; mf < 4; ++mf)
        #pragma unroll
        for (int nf = 0; nf < 4; ++nf)
            #pragma unroll
            for (int r = 0; r < 4; ++r) {
                int row = m0 + wm + mf * 16 + lg * 4 + r;
                int col = n0 + wn + nf * 16 + lr;
                if (row < M) C8[(size_t)row * 256 + col] = f2fp8(acc[mf][nf][r]);
            }
    {   // fused att logits (head = 64-col slice, wave-exclusive), full precision
        float asr[4], adr[4];
        #pragma unroll
        for (int nf = 0; nf < 4; ++nf) {
            int col = n0 + wn + nf * 16 + lr;
            asr[nf] = att_src[col];
            adr[nf] = att_dst[col];
        }
        const int hidx = (n0 + wn) >> 6;
        #pragma unroll
        for (int mf = 0; mf < 4; ++mf)
            #pragma unroll
            for (int r = 0; r < 4; ++r) {
                float s = 0.f, d = 0.f;
                #pragma unroll
                for (int nf = 0; nf < 4; ++nf) {
                    float v = acc[mf][nf][r];
                    s += v * asr[nf]; d += v * adr[nf];
                }
                #pragma unroll
                for (int o = 8; o; o >>= 1) {
                    s += __shfl_xor(s, o, 64);
                    d += __shfl_xor(d, o, 64);
                }
                int row = m0 + wm + mf * 16 + lg * 4 + r;
                if (lr == 0 && row < M) {
                    as_out[row * 4 + hidx] = s;
                    ad_out[row * 4 + hidx] = d;
                }
            }
    }
}

// ---------------- GEMM2 (BN=64), fp8 C, fused att logits --------------------
__global__ __launch_bounds__(256) void gemm2_swz(
    const ushort_t* __restrict__ A, const ushort_t* __restrict__ Bt,
    uchar_t* __restrict__ C8, int M,
    const float* __restrict__ att_src, const float* __restrict__ att_dst,
    float* __restrict__ as_out, float* __restrict__ ad_out) {
    __shared__ ushort_t As[128 * 64];
    __shared__ ushort_t Bs[64 * 64];
    const int tid = threadIdx.x;
    const int w = tid >> 6, lane = tid & 63;
    const int lr = lane & 15, lg = lane >> 4;
    const int m0 = blockIdx.x * 128;
    const int wm = w * 32;
    f32x4 acc[2][4];
    #pragma unroll
    for (int i = 0; i < 2; ++i)
        #pragma unroll
        for (int j = 0; j < 4; ++j) acc[i][j] = (f32x4){0.f, 0.f, 0.f, 0.f};

    const int rsub = lane >> 3;
    const int gc = (lane & 7) ^ rsub;

    for (int k0 = 0; k0 < 256; k0 += 64) {
        #pragma unroll
        for (int t = 0; t < 4; ++t) {
            int slot = t * 4 + w;
            int row = slot * 8 + rsub;
            int gm = m0 + row; if (gm > M - 1) gm = M - 1;
            gload_lds16((const char*)A + (size_t)gm * 512 + k0 * 2 + gc * 16,
                        (char*)As + slot * 1024);
        }
        #pragma unroll
        for (int t = 0; t < 2; ++t) {
            int slot = t * 4 + w;
            int row = slot * 8 + rsub;
            gload_lds16((const char*)Bt + (size_t)row * 512 + k0 * 2 + gc * 16,
                        (char*)Bs + slot * 1024);
        }
        __syncthreads();
        #pragma unroll
        for (int kk = 0; kk < 2; ++kk) {
            const int chunk = kk * 4 + lg;
            bf16x8 av[2], bv[4];
            #pragma unroll
            for (int mf = 0; mf < 2; ++mf) {
                int row = wm + mf * 16 + lr;
                av[mf] = *reinterpret_cast<const bf16x8*>(&As[row * 64 + ((chunk ^ (row & 7)) * 8)]);
            }
            #pragma unroll
            for (int nf = 0; nf < 4; ++nf) {
                int row = nf * 16 + lr;
                bv[nf] = *reinterpret_cast<const bf16x8*>(&Bs[row * 64 + ((chunk ^ (row & 7)) * 8)]);
            }
            #pragma unroll
            for (int mf = 0; mf < 2; ++mf)
                #pragma unroll
                for (int nf = 0; nf < 4; ++nf)
                    acc[mf][nf] = __builtin_amdgcn_mfma_f32_16x16x32_bf16(av[mf], bv[nf], acc[mf][nf], 0, 0, 0);
        }
        __syncthreads();
    }
    #pragma unroll
    for (int mf = 0; mf < 2; ++mf)
        #pragma unroll
        for (int nf = 0; nf < 4; ++nf)
            #pragma unroll
            for (int r = 0; r < 4; ++r) {
                int row = m0 + wm + mf * 16 + lg * 4 + r;
                int col = nf * 16 + lr;
                if (row < M) C8[(size_t)row * 64 + col] = f2fp8(acc[mf][nf][r]);
            }
    {
        float asr[4], adr[4];
        #pragma unroll
        for (int nf = 0; nf < 4; ++nf) {
            asr[nf] = att_src[nf * 16 + lr];
            adr[nf] = att_dst[nf * 16 + lr];
        }
        #pragma unroll
        for (int mf = 0; mf < 2; ++mf)
            #pragma unroll
            for (int r = 0; r < 4; ++r) {
                float s = 0.f, d = 0.f;
                #pragma unroll
                for (int nf = 0; nf < 4; ++nf) {
                    float v = acc[mf][nf][r];
                    s += v * asr[nf]; d += v * adr[nf];
                }
                #pragma unroll
                for (int o = 8; o; o >>= 1) {
                    s += __shfl_xor(s, o, 64);
                    d += __shfl_xor(d, o, 64);
                }
                int row = m0 + wm + mf * 16 + lg * 4 + r;
                if (lr == 0 && row < M) { as_out[row] = s; ad_out[row] = d; }
            }
    }
}

// ---------------- GAT1 aggregation: fp8 gather, 64 lanes x dword, 8-deep ----
// (R10-proven structure: 32 VGPR, ~65% occupancy; the uint4 variant regressed)
__global__ void gat1_agg(const uint_t* __restrict__ h1u, const float* __restrict__ a1s,
                         const float* __restrict__ a1d, const int* __restrict__ rowptr,
                         const int* __restrict__ csr, const float* __restrict__ bias,
                         ushort_t* __restrict__ out1b) {
    int i = (blockIdx.x * blockDim.x + threadIdx.x) >> 6;
    int lane = threadIdx.x & 63;
    if (i >= N_NODES) return;
    int hd = lane >> 4;                        // channels lane*4.. -> head lane/16
    int beg = rowptr[i], end = rowptr[i + 1];
    float ad  = a1d[i * 4 + hd];
    float p = __expf(leaky02(a1s[i * 4 + hd] + ad));   // self loop
    float den = p;
    float acc0, acc1, acc2, acc3;
    {
        uint_t v = h1u[(size_t)i * 64 + lane];
        f32x2 lo = __builtin_amdgcn_cvt_pk_f32_fp8(v, false);
        f32x2 hi = __builtin_amdgcn_cvt_pk_f32_fp8(v, true);
        acc0 = p * lo[0]; acc1 = p * lo[1]; acc2 = p * hi[0]; acc3 = p * hi[1];
    }
    int e = beg;
    for (; e + 8 <= end; e += 8) {
        int s[8]; float b[8]; uint_t v[8];
        #pragma unroll
        for (int j = 0; j < 8; ++j) s[j] = csr[e + j];
        #pragma unroll
        for (int j = 0; j < 8; ++j) b[j] = a1s[s[j] * 4 + hd];
        #pragma unroll
        for (int j = 0; j < 8; ++j) v[j] = h1u[(size_t)s[j] * 64 + lane];
        #pragma unroll
        for (int j = 0; j < 8; ++j) {
            float q = __expf(leaky02(b[j] + ad));
            f32x2 lo = __builtin_amdgcn_cvt_pk_f32_fp8(v[j], false);
            f32x2 hi = __builtin_amdgcn_cvt_pk_f32_fp8(v[j], true);
            den += q;
            acc0 += q * lo[0]; acc1 += q * lo[1];
            acc2 += q * hi[0]; acc3 += q * hi[1];
        }
    }
    for (; e < end; ++e) {
        int s = csr[e];
        float q = __expf(leaky02(a1s[s * 4 + hd] + ad));
        uint_t v = h1u[(size_t)s * 64 + lane];
        f32x2 lo = __builtin_amdgcn_cvt_pk_f32_fp8(v, false);
        f32x2 hi = __builtin_amdgcn_cvt_pk_f32_fp8(v, true);
        den += q;
        acc0 += q * lo[0]; acc1 += q * lo[1];
        acc2 += q * hi[0]; acc3 += q * hi[1];
    }
    float inv = 1.f / (den + 1e-16f);
    ushort4 ov;
    ov.x = f2bf(fmaxf(acc0 * inv + bias[lane * 4 + 0], 0.f));
    ov.y = f2bf(fmaxf(acc1 * inv + bias[lane * 4 + 1], 0.f));
    ov.z = f2bf(fmaxf(acc2 * inv + bias[lane * 4 + 2], 0.f));
    ov.w = f2bf(fmaxf(acc3 * inv + bias[lane * 4 + 3], 0.f));
    *reinterpret_cast<ushort4*>(&out1b[(size_t)i * 256 + lane * 4]) = ov;
}

// ---------------- GAT2 + pool: fp8 gather + block-level LDS pool reduce -----
__global__ void gat2_agg_pool(const uint_t* __restrict__ h2u, const float* __restrict__ a2s,
                              const float* __restrict__ a2d, const int* __restrict__ rowptr,
                              const int* __restrict__ csr, const float* __restrict__ bias,
                              const int* __restrict__ batch, float* __restrict__ slots) {
    __shared__ float fv[4][64];
    __shared__ int bg[4];
    int w = threadIdx.x >> 6;
    int i = blockIdx.x * 4 + w;                // N_NODES = 4*12500 exactly
    int lane = threadIdx.x & 63;
    int g = lane >> 4, c = lane & 15;
    int beg = rowptr[i], end = rowptr[i + 1];
    float ad = a2d[i];
    float acc0 = 0.f, acc1 = 0.f, acc2 = 0.f, acc3 = 0.f, qsum = 0.f;
    if (g == 0) {   // self loop counted once
        float p = __expf(leaky02(a2s[i] + ad));
        uint_t v = h2u[(size_t)i * 16 + c];
        f32x2 lo = __builtin_amdgcn_cvt_pk_f32_fp8(v, false);
        f32x2 hi = __builtin_amdgcn_cvt_pk_f32_fp8(v, true);
        qsum = p;
        acc0 = p * lo[0]; acc1 = p * lo[1]; acc2 = p * hi[0]; acc3 = p * hi[1];
    }
    for (int e = beg; e < end; e += 16) {
        int  s[4]; float q[4]; uint_t hv[4];
        #pragma unroll
        for (int j = 0; j < 4; ++j) {
            int idx = e + j * 4 + g;
            s[j] = (idx < end) ? csr[idx] : i;
        }
        #pragma unroll
        for (int j = 0; j < 4; ++j) hv[j] = h2u[(size_t)s[j] * 16 + c];
        #pragma unroll
        for (int j = 0; j < 4; ++j) {
            int idx = e + j * 4 + g;
            q[j] = (idx < end) ? __expf(leaky02(a2s[s[j]] + ad)) : 0.f;
        }
        #pragma unroll
        for (int j = 0; j < 4; ++j) {
            f32x2 lo = __builtin_amdgcn_cvt_pk_f32_fp8(hv[j], false);
            f32x2 hi = __builtin_amdgcn_cvt_pk_f32_fp8(hv[j], true);
            qsum += q[j];
            acc0 += q[j] * lo[0]; acc1 += q[j] * lo[1];
            acc2 += q[j] * hi[0]; acc3 += q[j] * hi[1];
        }
    }
    qsum += __shfl_xor(qsum, 16, 64); qsum += __shfl_xor(qsum, 32, 64);
    acc0 += __shfl_xor(acc0, 16, 64); acc0 += __shfl_xor(acc0, 32, 64);
    acc1 += __shfl_xor(acc1, 16, 64); acc1 += __shfl_xor(acc1, 32, 64);
    acc2 += __shfl_xor(acc2, 16, 64); acc2 += __shfl_xor(acc2, 32, 64);
    acc3 += __shfl_xor(acc3, 16, 64); acc3 += __shfl_xor(acc3, 32, 64);
    if (g == 0) {
        float inv = 1.f / (qsum + 1e-16f);
        fv[w][c * 4 + 0] = fmaxf(acc0 * inv + bias[c * 4 + 0], 0.f);
        fv[w][c * 4 + 1] = fmaxf(acc1 * inv + bias[c * 4 + 1], 0.f);
        fv[w][c * 4 + 2] = fmaxf(acc2 * inv + bias[c * 4 + 2], 0.f);
        fv[w][c * 4 + 3] = fmaxf(acc3 * inv + bias[c * 4 + 3], 0.f);
        if (c == 0) bg[w] = batch[i];
    }
    __syncthreads();
    if (w == 0) {
        int slot = blockIdx.x & (NSLOT - 1);
        int g0 = bg[0];
        float s = 0.f;
        #pragma unroll
        for (int r = 0; r < 4; ++r) if (bg[r] == g0) s += fv[r][lane];
        atomicAdd(&slots[((size_t)g0 * NSLOT + slot) * 64 + lane], s);
        #pragma unroll
        for (int r = 1; r < 4; ++r)
            if (bg[r] != g0)
                atomicAdd(&slots[((size_t)bg[r] * NSLOT + slot) * 64 + lane], fv[r][lane]);
    }
}

// ---------------- slot-reduce + classifier (one block per graph) -----------
__global__ void cls_kernel(const float* __restrict__ slots, const int* __restrict__ batch,
                           const float* __restrict__ w1, const float* __restrict__ b1,
                           const float* __restrict__ w2, const float* __restrict__ b2,
                           float* __restrict__ out) {
    int g = blockIdx.x;
    int t = threadIdx.x;   // 64
    __shared__ float p[64];
    __shared__ float hbuf[32];
    float s = 0.f;
    #pragma unroll
    for (int sl = 0; sl < NSLOT; ++sl) s += slots[((size_t)g * NSLOT + sl) * 64 + t];
    int lo = lower_bound_i(batch, N_NODES, g);
    int hi = lower_bound_i(batch, N_NODES, g + 1);
    p[t] = s / fmaxf((float)(hi - lo), 1.f);
    __syncthreads();
    if (t < 32) {
        float a = b1[t];
        #pragma unroll
        for (int c = 0; c < 64; ++c) a += p[c] * w1[c * 32 + t];
        hbuf[t] = fmaxf(a, 0.f);
    }
    __syncthreads();
    if (t == 0) {
        float logit[16];
        float mx = -INFINITY;
        #pragma unroll
        for (int o = 0; o < 16; ++o) {
            float a = b2[o];
            #pragma unroll
            for (int j = 0; j < 32; ++j) a += hbuf[j] * w2[j * 16 + o];
            logit[o] = a;
            mx = fmaxf(mx, a);
        }
        float den = 0.f;
        #pragma unroll
        for (int o = 0; o < 16; ++o) den += __expf(logit[o] - mx);
        float lse = mx + logf(den);
        #pragma unroll
        for (int o = 0; o < 16; ++o) out[g * 16 + o] = logit[o] - lse;
    }
}

// ---------------- launch -----------------------------------------------------
extern "C" void kernel_launch(void* const* d_in, const int* in_sizes, int n_in,
                              void* d_out, int out_size, void* d_ws, size_t ws_size,
                              hipStream_t stream) {
    const float* x     = (const float*)d_in[0];
    const int*   ei    = (const int*)d_in[1];
    const int*   batch = (const int*)d_in[2];
    // d_in[3..6] = signal-attention MLP: softmax over size-1 axis == identity -> unused
    const float* g1_w  = (const float*)d_in[7];
    const float* g1_as = (const float*)d_in[8];
    const float* g1_ad = (const float*)d_in[9];
    const float* g1_b  = (const float*)d_in[10];
    const float* g2_w  = (const float*)d_in[11];
    const float* g2_as = (const float*)d_in[12];
    const float* g2_ad = (const float*)d_in[13];
    const float* g2_b  = (const float*)d_in[14];
    const float* cl_w1 = (const float*)d_in[15];
    const float* cl_b1 = (const float*)d_in[16];
    const float* cl_w2 = (const float*)d_in[17];
    const float* cl_b2 = (const float*)d_in[18];

    char* ws = (char*)d_ws;
    ushort_t* xb     = (ushort_t*)(ws + OFF_XB);
    uchar_t*  h1f8   = (uchar_t*)(ws + OFF_H1F8);
    ushort_t* out1b  = (ushort_t*)(ws + OFF_OUT1B);
    uchar_t*  h2f8   = (uchar_t*)(ws + OFF_H2F8);
    float*    a1s    = (float*)(ws + OFF_A1S);
    float*    a1d    = (float*)(ws + OFF_A1D);
    float*    a2s    = (float*)(ws + OFF_A2S);
    float*    a2d    = (float*)(ws + OFF_A2D);
    int*      cnt    = (int*)(ws + OFF_CNT);
    float*    slots  = (float*)(ws + OFF_SLOTS);
    int*      rowptr = (int*)(ws + OFF_ROWPTR);
    int*      cursor = (int*)(ws + OFF_CURSOR);
    int*      csr    = (int*)(ws + OFF_CSR);
    int*      part   = (int*)(ws + OFF_PART);
    ushort_t* w1t    = (ushort_t*)(ws + OFF_W1T);
    ushort_t* w2t    = (ushort_t*)(ws + OFF_W2T);

    const int npart = (N_NODES + 255) / 256;   // 196

    // single memset: cnt + slots contiguous
    hipMemsetAsync(cnt, 0, 200000 + N_GRAPHS * NSLOT * HID * sizeof(float), stream);

    prep_all<<<N_NODES * 256 / 4 / 256, 256, 0, stream>>>(x, xb, g1_w, g2_w, w1t, w2t, ei, cnt);

    scan_partial<<<npart, 256, 0, stream>>>(cnt, part);
    scan_final2<<<npart, 256, 0, stream>>>(cnt, part, rowptr, cursor, npart);
    scatter_kernel<<<(N_EDGES + 255) / 256, 256, 0, stream>>>(ei, cursor, csr);

    // GAT1: h1(fp8) = x @ g1_w + fused att logits (f32)
    gemm1_swz<<<2 * ((N_NODES + 127) / 128), 256, 0, stream>>>(
        xb, w1t, h1f8, N_NODES, g1_as, g1_ad, a1s, a1d);
    gat1_agg<<<(N_NODES + 3) / 4, 256, 0, stream>>>(
        (const uint_t*)h1f8, a1s, a1d, rowptr, csr, g1_b, out1b);

    // GAT2: h2(fp8) = out1 @ g2_w + fused att logits; agg+pool
    gemm2_swz<<<(N_NODES + 127) / 128, 256, 0, stream>>>(
        out1b, w2t, h2f8, N_NODES, g2_as, g2_ad, a2s, a2d);
    gat2_agg_pool<<<N_NODES / 4, 256, 0, stream>>>(
        (const uint_t*)h2f8, a2s, a2d, rowptr, csr, g2_b, batch, slots);

    cls_kernel<<<N_GRAPHS, 64, 0, stream>>>(slots, batch, cl_w1, cl_b1, cl_w2, cl_b2, (float*)d_out);
}

// Round 14
// 187.265 us; speedup vs baseline: 7.6189x; 1.1562x over previous
//
#include <hip/hip_runtime.h>
#include <math.h>

#define N_NODES 50000
#define N_EDGES 800000
#define N_GRAPHS 128
#define IN_CH 256
#define HID 64
#define HEADS 4
#define OUT_CH 16
#define NSLOT 32

typedef unsigned short ushort_t;
typedef unsigned int uint_t;
typedef unsigned char uchar_t;
typedef __attribute__((ext_vector_type(8))) short bf16x8;
typedef __attribute__((ext_vector_type(4))) float f32x4;
typedef __attribute__((ext_vector_type(2))) float f32x2;

// ---------------- workspace layout (bytes, 64-aligned) ----------------
static const size_t OFF_XB     = 0;           // x bf16       25,600,000
static const size_t OFF_H1F8   = 25600000;    // h1 fp8       12,800,000
static const size_t OFF_OUT1B  = 38400000;    // out1 bf16    25,600,000
static const size_t OFF_H2F8   = 64000000;    // h2 fp8        3,200,000
static const size_t OFF_A1S    = 67200000;    //                 800,000
static const size_t OFF_A1D    = 68000000;    //                 800,000
static const size_t OFF_A2S    = 68800000;    //                 200,000
static const size_t OFF_A2D    = 69000000;    //                 200,000
// cnt + slots contiguous -> ONE memset
static const size_t OFF_CNT    = 69200000;    //                 200,000
static const size_t OFF_SLOTS  = 69400000;    //               1,048,576
static const size_t OFF_ROWPTR = 70448640;    //                 200,064
static const size_t OFF_CURSOR = 70648704;    //                 200,000 (unused now)
static const size_t OFF_CSR    = 70848704;    //               3,200,000
static const size_t OFF_PART   = 74048704;    //                   1,024
static const size_t OFF_W1T    = 74049728;    //                 131,072
static const size_t OFF_W2T    = 74180800;    //                  32,768
static const size_t OFF_POS    = 74213568;    //               3,200,000 (edge rank in dst row)

#define DEV static __device__ __forceinline__

DEV float leaky02(float v) { return v > 0.f ? v : 0.2f * v; }
DEV float bf2f(ushort_t s) { return __uint_as_float(((uint_t)s) << 16); }
DEV ushort_t f2bf(float f) {
    uint_t u = __float_as_uint(f);
    return (ushort_t)((u + 0x7FFFu + ((u >> 16) & 1u)) >> 16);
}
DEV uchar_t f2fp8(float f) {
    int p = __builtin_amdgcn_cvt_pk_fp8_f32(f, 0.f, 0, false);
    return (uchar_t)(p & 0xFF);
}
DEV int wred_sum_i(int v) {
    #pragma unroll
    for (int o = 32; o; o >>= 1) v += __shfl_xor(v, o, 64);
    return v;
}
DEV int lower_bound_i(const int* a, int n, int key) {
    int lo = 0, hi = n;
    while (lo < hi) { int mid = (lo + hi) >> 1; if (a[mid] < key) lo = mid + 1; else hi = mid; }
    return lo;
}
DEV void gload_lds16(const void* g, void* l) {
    __builtin_amdgcn_global_load_lds(
        (const __attribute__((address_space(1))) uint_t*)g,
        (__attribute__((address_space(3))) uint_t*)l, 16, 0, 0);
}

// ---------------- fused prep: x->bf16, weights, degree count + edge rank ----
__global__ void prep_all(const float* __restrict__ x, ushort_t* __restrict__ xb,
                         const float* __restrict__ g1w, const float* __restrict__ g2w,
                         ushort_t* __restrict__ w1t, ushort_t* __restrict__ w2t,
                         const int* __restrict__ ei, int* __restrict__ cnt,
                         int* __restrict__ pos) {
    int tid = blockIdx.x * 256 + threadIdx.x;     // 3,200,000 threads
    {   // convert x, one float4 per thread
        float4 v = *reinterpret_cast<const float4*>(&x[(size_t)tid * 4]);
        ushort4 o;
        o.x = f2bf(v.x); o.y = f2bf(v.y); o.z = f2bf(v.z); o.w = f2bf(v.w);
        *reinterpret_cast<ushort4*>(&xb[(size_t)tid * 4]) = o;
    }
    if (tid < N_EDGES) pos[tid] = atomicAdd(&cnt[ei[N_EDGES + tid]], 1);  // rank in dst row
    if (tid < 256 * 256) {                        // w1t[n][k] = g1w[k][n]
        int n = tid >> 8, k = tid & 255;
        w1t[tid] = f2bf(g1w[k * 256 + n]);
    }
    if (tid < 64 * 256) {                         // w2t[n][k] = g2w[k][n]
        int n = tid >> 8, k = tid & 255;
        w2t[tid] = f2bf(g2w[k * 64 + n]);
    }
}

// ---------------- CSR build: 2-kernel scan ----------------------------------
__global__ void scan_partial(const int* __restrict__ cnt, int* __restrict__ part) {
    __shared__ int wsum[4];
    int i = blockIdx.x * 256 + threadIdx.x;
    int v = (i < N_NODES) ? cnt[i] : 0;
    v = wred_sum_i(v);
    if ((threadIdx.x & 63) == 0) wsum[threadIdx.x >> 6] = v;
    __syncthreads();
    if (threadIdx.x == 0) part[blockIdx.x] = wsum[0] + wsum[1] + wsum[2] + wsum[3];
}

__global__ void scan_final2(const int* __restrict__ cnt, const int* __restrict__ part,
                            int* __restrict__ rowptr, int npart) {
    __shared__ int buf[256];
    __shared__ int ws4[4];
    int b = blockIdx.x, tid = threadIdx.x;
    int pv = (tid < b && tid < npart) ? part[tid] : 0;
    pv = wred_sum_i(pv);
    if ((tid & 63) == 0) ws4[tid >> 6] = pv;
    __syncthreads();
    int base = ws4[0] + ws4[1] + ws4[2] + ws4[3];
    int i = b * 256 + tid;
    int v = (i < N_NODES) ? cnt[i] : 0;
    buf[tid] = v; __syncthreads();
    for (int off = 1; off < 256; off <<= 1) {
        int t = (tid >= off) ? buf[tid - off] : 0;
        __syncthreads();
        buf[tid] += t;
        __syncthreads();
    }
    if (i < N_NODES) rowptr[i + 1] = buf[tid] + base;
    if (i == 0) rowptr[0] = 0;
}

// scatter without atomics: position = rowptr[dst] + precomputed rank
__global__ void scatter_kernel(const int* __restrict__ ei, const int* __restrict__ rowptr,
                               const int* __restrict__ pos, int* __restrict__ csr) {
    int e = blockIdx.x * blockDim.x + threadIdx.x;
    if (e < N_EDGES) {
        int d = ei[N_EDGES + e];
        csr[rowptr[d] + pos[e]] = ei[e];
    }
}

// ---------------- GEMM1: 128x128 tile, swizzled LDS, fp8 C, fused logits ----
__global__ __launch_bounds__(256) void gemm1_swz(
    const ushort_t* __restrict__ A, const ushort_t* __restrict__ Bt,
    uchar_t* __restrict__ C8, int M,
    const float* __restrict__ att_src, const float* __restrict__ att_dst,
    float* __restrict__ as_out, float* __restrict__ ad_out) {
    __shared__ ushort_t As[128 * 64];
    __shared__ ushort_t Bs[128 * 64];
    const int tid = threadIdx.x;
    const int w = tid >> 6, lane = tid & 63;
    const int lr = lane & 15, lg = lane >> 4;
    const int m0 = (blockIdx.x >> 1) * 128, n0 = (blockIdx.x & 1) * 128;
    const int wm = (w >> 1) * 64, wn = (w & 1) * 64;
    f32x4 acc[4][4];
    #pragma unroll
    for (int i = 0; i < 4; ++i)
        #pragma unroll
        for (int j = 0; j < 4; ++j) acc[i][j] = (f32x4){0.f, 0.f, 0.f, 0.f};

    const int rsub = lane >> 3;
    const int gc = (lane & 7) ^ rsub;

    for (int k0 = 0; k0 < 256; k0 += 64) {
        #pragma unroll
        for (int t = 0; t < 4; ++t) {
            int slot = t * 4 + w;
            int row = slot * 8 + rsub;
            int gm = m0 + row; if (gm > M - 1) gm = M - 1;
            gload_lds16((const char*)A + (size_t)gm * 512 + k0 * 2 + gc * 16,
                        (char*)As + slot * 1024);
        }
        #pragma unroll
        for (int t = 0; t < 4; ++t) {
            int slot = t * 4 + w;
            int row = slot * 8 + rsub;
            gload_lds16((const char*)Bt + (size_t)(n0 + row) * 512 + k0 * 2 + gc * 16,
                        (char*)Bs + slot * 1024);
        }
        __syncthreads();
        #pragma unroll
        for (int kk = 0; kk < 2; ++kk) {
            const int chunk = kk * 4 + lg;
            bf16x8 av[4], bv[4];
            #pragma unroll
            for (int mf = 0; mf < 4; ++mf) {
                int row = wm + mf * 16 + lr;
                av[mf] = *reinterpret_cast<const bf16x8*>(&As[row * 64 + ((chunk ^ (row & 7)) * 8)]);
            }
            #pragma unroll
            for (int nf = 0; nf < 4; ++nf) {
                int row = wn + nf * 16 + lr;
                bv[nf] = *reinterpret_cast<const bf16x8*>(&Bs[row * 64 + ((chunk ^ (row & 7)) * 8)]);
            }
            #pragma unroll
            for (int mf = 0; mf < 4; ++mf)
                #pragma unroll
                for (int nf = 0; nf < 4; ++nf)
                    acc[mf][nf] = __builtin_amdgcn_mfma_f32_16x16x32_bf16(av[mf], bv[nf], acc[mf][nf], 0, 0, 0);
        }
        __syncthreads();
    }
    #pragma unroll
    for (int mf = 0; mf < 4; ++mf)
        #pragma unroll
        for (int nf = 0; nf < 4; ++nf)
            #pragma unroll
            for (int r = 0; r < 4; ++r) {
                int row = m0 + wm + mf * 16 + lg * 4 + r;
                int col = n0 + wn + nf * 16 + lr;
                if (row < M) C8[(size_t)row * 256 + col] = f2fp8(acc[mf][nf][r]);
            }
    {   // fused att logits (head = 64-col slice, wave-exclusive), full precision
        float asr[4], adr[4];
        #pragma unroll
        for (int nf = 0; nf < 4; ++nf) {
            int col = n0 + wn + nf * 16 + lr;
            asr[nf] = att_src[col];
            adr[nf] = att_dst[col];
        }
        const int hidx = (n0 + wn) >> 6;
        #pragma unroll
        for (int mf = 0; mf < 4; ++mf)
            #pragma unroll
            for (int r = 0; r < 4; ++r) {
                float s = 0.f, d = 0.f;
                #pragma unroll
                for (int nf = 0; nf < 4; ++nf) {
                    float v = acc[mf][nf][r];
                    s += v * asr[nf]; d += v * adr[nf];
                }
                #pragma unroll
                for (int o = 8; o; o >>= 1) {
                    s += __shfl_xor(s, o, 64);
                    d += __shfl_xor(d, o, 64);
                }
                int row = m0 + wm + mf * 16 + lg * 4 + r;
                if (lr == 0 && row < M) {
                    as_out[row * 4 + hidx] = s;
                    ad_out[row * 4 + hidx] = d;
                }
            }
    }
}

// ---------------- GEMM2 (BN=64), fp8 C, fused att logits --------------------
__global__ __launch_bounds__(256) void gemm2_swz(
    const ushort_t* __restrict__ A, const ushort_t* __restrict__ Bt,
    uchar_t* __restrict__ C8, int M,
    const float* __restrict__ att_src, const float* __restrict__ att_dst,
    float* __restrict__ as_out, float* __restrict__ ad_out) {
    __shared__ ushort_t As[128 * 64];
    __shared__ ushort_t Bs[64 * 64];
    const int tid = threadIdx.x;
    const int w = tid >> 6, lane = tid & 63;
    const int lr = lane & 15, lg = lane >> 4;
    const int m0 = blockIdx.x * 128;
    const int wm = w * 32;
    f32x4 acc[2][4];
    #pragma unroll
    for (int i = 0; i < 2; ++i)
        #pragma unroll
        for (int j = 0; j < 4; ++j) acc[i][j] = (f32x4){0.f, 0.f, 0.f, 0.f};

    const int rsub = lane >> 3;
    const int gc = (lane & 7) ^ rsub;

    for (int k0 = 0; k0 < 256; k0 += 64) {
        #pragma unroll
        for (int t = 0; t < 4; ++t) {
            int slot = t * 4 + w;
            int row = slot * 8 + rsub;
            int gm = m0 + row; if (gm > M - 1) gm = M - 1;
            gload_lds16((const char*)A + (size_t)gm * 512 + k0 * 2 + gc * 16,
                        (char*)As + slot * 1024);
        }
        #pragma unroll
        for (int t = 0; t < 2; ++t) {
            int slot = t * 4 + w;
            int row = slot * 8 + rsub;
            gload_lds16((const char*)Bt + (size_t)row * 512 + k0 * 2 + gc * 16,
                        (char*)Bs + slot * 1024);
        }
        __syncthreads();
        #pragma unroll
        for (int kk = 0; kk < 2; ++kk) {
            const int chunk = kk * 4 + lg;
            bf16x8 av[2], bv[4];
            #pragma unroll
            for (int mf = 0; mf < 2; ++mf) {
                int row = wm + mf * 16 + lr;
                av[mf] = *reinterpret_cast<const bf16x8*>(&As[row * 64 + ((chunk ^ (row & 7)) * 8)]);
            }
            #pragma unroll
            for (int nf = 0; nf < 4; ++nf) {
                int row = nf * 16 + lr;
                bv[nf] = *reinterpret_cast<const bf16x8*>(&Bs[row * 64 + ((chunk ^ (row & 7)) * 8)]);
            }
            #pragma unroll
            for (int mf = 0; mf < 2; ++mf)
                #pragma unroll
                for (int nf = 0; nf < 4; ++nf)
                    acc[mf][nf] = __builtin_amdgcn_mfma_f32_16x16x32_bf16(av[mf], bv[nf], acc[mf][nf], 0, 0, 0);
        }
        __syncthreads();
    }
    #pragma unroll
    for (int mf = 0; mf < 2; ++mf)
        #pragma unroll
        for (int nf = 0; nf < 4; ++nf)
            #pragma unroll
            for (int r = 0; r < 4; ++r) {
                int row = m0 + wm + mf * 16 + lg * 4 + r;
                int col = nf * 16 + lr;
                if (row < M) C8[(size_t)row * 64 + col] = f2fp8(acc[mf][nf][r]);
            }
    {
        float asr[4], adr[4];
        #pragma unroll
        for (int nf = 0; nf < 4; ++nf) {
            asr[nf] = att_src[nf * 16 + lr];
            adr[nf] = att_dst[nf * 16 + lr];
        }
        #pragma unroll
        for (int mf = 0; mf < 2; ++mf)
            #pragma unroll
            for (int r = 0; r < 4; ++r) {
                float s = 0.f, d = 0.f;
                #pragma unroll
                for (int nf = 0; nf < 4; ++nf) {
                    float v = acc[mf][nf][r];
                    s += v * asr[nf]; d += v * adr[nf];
                }
                #pragma unroll
                for (int o = 8; o; o >>= 1) {
                    s += __shfl_xor(s, o, 64);
                    d += __shfl_xor(d, o, 64);
                }
                int row = m0 + wm + mf * 16 + lg * 4 + r;
                if (lr == 0 && row < M) { as_out[row] = s; ad_out[row] = d; }
            }
    }
}

// ---------------- GAT1 aggregation: fp8 gather, 64 lanes x dword, 8-deep ----
__global__ void gat1_agg(const uint_t* __restrict__ h1u, const float* __restrict__ a1s,
                         const float* __restrict__ a1d, const int* __restrict__ rowptr,
                         const int* __restrict__ csr, const float* __restrict__ bias,
                         ushort_t* __restrict__ out1b) {
    int i = (blockIdx.x * blockDim.x + threadIdx.x) >> 6;
    int lane = threadIdx.x & 63;
    if (i >= N_NODES) return;
    int hd = lane >> 4;                        // channels lane*4.. -> head lane/16
    int beg = rowptr[i], end = rowptr[i + 1];
    float ad  = a1d[i * 4 + hd];
    float p = __expf(leaky02(a1s[i * 4 + hd] + ad));   // self loop
    float den = p;
    float acc0, acc1, acc2, acc3;
    {
        uint_t v = h1u[(size_t)i * 64 + lane];
        f32x2 lo = __builtin_amdgcn_cvt_pk_f32_fp8(v, false);
        f32x2 hi = __builtin_amdgcn_cvt_pk_f32_fp8(v, true);
        acc0 = p * lo[0]; acc1 = p * lo[1]; acc2 = p * hi[0]; acc3 = p * hi[1];
    }
    int e = beg;
    for (; e + 8 <= end; e += 8) {
        int s[8]; float b[8]; uint_t v[8];
        #pragma unroll
        for (int j = 0; j < 8; ++j) s[j] = csr[e + j];
        #pragma unroll
        for (int j = 0; j < 8; ++j) b[j] = a1s[s[j] * 4 + hd];
        #pragma unroll
        for (int j = 0; j < 8; ++j) v[j] = h1u[(size_t)s[j] * 64 + lane];
        #pragma unroll
        for (int j = 0; j < 8; ++j) {
            float q = __expf(leaky02(b[j] + ad));
            f32x2 lo = __builtin_amdgcn_cvt_pk_f32_fp8(v[j], false);
            f32x2 hi = __builtin_amdgcn_cvt_pk_f32_fp8(v[j], true);
            den += q;
            acc0 += q * lo[0]; acc1 += q * lo[1];
            acc2 += q * hi[0]; acc3 += q * hi[1];
        }
    }
    for (; e < end; ++e) {
        int s = csr[e];
        float q = __expf(leaky02(a1s[s * 4 + hd] + ad));
        uint_t v = h1u[(size_t)s * 64 + lane];
        f32x2 lo = __builtin_amdgcn_cvt_pk_f32_fp8(v, false);
        f32x2 hi = __builtin_amdgcn_cvt_pk_f32_fp8(v, true);
        den += q;
        acc0 += q * lo[0]; acc1 += q * lo[1];
        acc2 += q * hi[0]; acc3 += q * hi[1];
    }
    float inv = 1.f / (den + 1e-16f);
    ushort4 ov;
    ov.x = f2bf(fmaxf(acc0 * inv + bias[lane * 4 + 0], 0.f));
    ov.y = f2bf(fmaxf(acc1 * inv + bias[lane * 4 + 1], 0.f));
    ov.z = f2bf(fmaxf(acc2 * inv + bias[lane * 4 + 2], 0.f));
    ov.w = f2bf(fmaxf(acc3 * inv + bias[lane * 4 + 3], 0.f));
    *reinterpret_cast<ushort4*>(&out1b[(size_t)i * 256 + lane * 4]) = ov;
}

// ---------------- GAT2 + pool: fp8 gather + block-level LDS pool reduce -----
__global__ void gat2_agg_pool(const uint_t* __restrict__ h2u, const float* __restrict__ a2s,
                              const float* __restrict__ a2d, const int* __restrict__ rowptr,
                              const int* __restrict__ csr, const float* __restrict__ bias,
                              const int* __restrict__ batch, float* __restrict__ slots) {
    __shared__ float fv[4][64];
    __shared__ int bg[4];
    int w = threadIdx.x >> 6;
    int i = blockIdx.x * 4 + w;                // N_NODES = 4*12500 exactly
    int lane = threadIdx.x & 63;
    int g = lane >> 4, c = lane & 15;
    int beg = rowptr[i], end = rowptr[i + 1];
    float ad = a2d[i];
    float acc0 = 0.f, acc1 = 0.f, acc2 = 0.f, acc3 = 0.f, qsum = 0.f;
    if (g == 0) {   // self loop counted once
        float p = __expf(leaky02(a2s[i] + ad));
        uint_t v = h2u[(size_t)i * 16 + c];
        f32x2 lo = __builtin_amdgcn_cvt_pk_f32_fp8(v, false);
        f32x2 hi = __builtin_amdgcn_cvt_pk_f32_fp8(v, true);
        qsum = p;
        acc0 = p * lo[0]; acc1 = p * lo[1]; acc2 = p * hi[0]; acc3 = p * hi[1];
    }
    for (int e = beg; e < end; e += 16) {
        int  s[4]; float q[4]; uint_t hv[4];
        #pragma unroll
        for (int j = 0; j < 4; ++j) {
            int idx = e + j * 4 + g;
            s[j] = (idx < end) ? csr[idx] : i;
        }
        #pragma unroll
        for (int j = 0; j < 4; ++j) hv[j] = h2u[(size_t)s[j] * 16 + c];
        #pragma unroll
        for (int j = 0; j < 4; ++j) {
            int idx = e + j * 4 + g;
            q[j] = (idx < end) ? __expf(leaky02(a2s[s[j]] + ad)) : 0.f;
        }
        #pragma unroll
        for (int j = 0; j < 4; ++j) {
            f32x2 lo = __builtin_amdgcn_cvt_pk_f32_fp8(hv[j], false);
            f32x2 hi = __builtin_amdgcn_cvt_pk_f32_fp8(hv[j], true);
            qsum += q[j];
            acc0 += q[j] * lo[0]; acc1 += q[j] * lo[1];
            acc2 += q[j] * hi[0]; acc3 += q[j] * hi[1];
        }
    }
    qsum += __shfl_xor(qsum, 16, 64); qsum += __shfl_xor(qsum, 32, 64);
    acc0 += __shfl_xor(acc0, 16, 64); acc0 += __shfl_xor(acc0, 32, 64);
    acc1 += __shfl_xor(acc1, 16, 64); acc1 += __shfl_xor(acc1, 32, 64);
    acc2 += __shfl_xor(acc2, 16, 64); acc2 += __shfl_xor(acc2, 32, 64);
    acc3 += __shfl_xor(acc3, 16, 64); acc3 += __shfl_xor(acc3, 32, 64);
    if (g == 0) {
        float inv = 1.f / (qsum + 1e-16f);
        fv[w][c * 4 + 0] = fmaxf(acc0 * inv + bias[c * 4 + 0], 0.f);
        fv[w][c * 4 + 1] = fmaxf(acc1 * inv + bias[c * 4 + 1], 0.f);
        fv[w][c * 4 + 2] = fmaxf(acc2 * inv + bias[c * 4 + 2], 0.f);
        fv[w][c * 4 + 3] = fmaxf(acc3 * inv + bias[c * 4 + 3], 0.f);
        if (c == 0) bg[w] = batch[i];
    }
    __syncthreads();
    if (w == 0) {
        int slot = blockIdx.x & (NSLOT - 1);
        int g0 = bg[0];
        float s = 0.f;
        #pragma unroll
        for (int r = 0; r < 4; ++r) if (bg[r] == g0) s += fv[r][lane];
        atomicAdd(&slots[((size_t)g0 * NSLOT + slot) * 64 + lane], s);
        #pragma unroll
        for (int r = 1; r < 4; ++r)
            if (bg[r] != g0)
                atomicAdd(&slots[((size_t)bg[r] * NSLOT + slot) * 64 + lane], fv[r][lane]);
    }
}

// ---------------- slot-reduce + classifier (one block per graph) -----------
__global__ void cls_kernel(const float* __restrict__ slots, const int* __restrict__ batch,
                           const float* __restrict__ w1, const float* __restrict__ b1,
                           const float* __restrict__ w2, const float* __restrict__ b2,
                           float* __restrict__ out) {
    int g = blockIdx.x;
    int t = threadIdx.x;   // 64
    __shared__ float p[64];
    __shared__ float hbuf[32];
    float s = 0.f;
    #pragma unroll
    for (int sl = 0; sl < NSLOT; ++sl) s += slots[((size_t)g * NSLOT + sl) * 64 + t];
    int lo = lower_bound_i(batch, N_NODES, g);
    int hi = lower_bound_i(batch, N_NODES, g + 1);
    p[t] = s / fmaxf((float)(hi - lo), 1.f);
    __syncthreads();
    if (t < 32) {
        float a = b1[t];
        #pragma unroll
        for (int c = 0; c < 64; ++c) a += p[c] * w1[c * 32 + t];
        hbuf[t] = fmaxf(a, 0.f);
    }
    __syncthreads();
    if (t == 0) {
        float logit[16];
        float mx = -INFINITY;
        #pragma unroll
        for (int o = 0; o < 16; ++o) {
            float a = b2[o];
            #pragma unroll
            for (int j = 0; j < 32; ++j) a += hbuf[j] * w2[j * 16 + o];
            logit[o] = a;
            mx = fmaxf(mx, a);
        }
        float den = 0.f;
        #pragma unroll
        for (int o = 0; o < 16; ++o) den += __expf(logit[o] - mx);
        float lse = mx + logf(den);
        #pragma unroll
        for (int o = 0; o < 16; ++o) out[g * 16 + o] = logit[o] - lse;
    }
}

// ---------------- launch -----------------------------------------------------
extern "C" void kernel_launch(void* const* d_in, const int* in_sizes, int n_in,
                              void* d_out, int out_size, void* d_ws, size_t ws_size,
                              hipStream_t stream) {
    const float* x     = (const float*)d_in[0];
    const int*   ei    = (const int*)d_in[1];
    const int*   batch = (const int*)d_in[2];
    // d_in[3..6] = signal-attention MLP: softmax over size-1 axis == identity -> unused
    const float* g1_w  = (const float*)d_in[7];
    const float* g1_as = (const float*)d_in[8];
    const float* g1_ad = (const float*)d_in[9];
    const float* g1_b  = (const float*)d_in[10];
    const float* g2_w  = (const float*)d_in[11];
    const float* g2_as = (const float*)d_in[12];
    const float* g2_ad = (const float*)d_in[13];
    const float* g2_b  = (const float*)d_in[14];
    const float* cl_w1 = (const float*)d_in[15];
    const float* cl_b1 = (const float*)d_in[16];
    const float* cl_w2 = (const float*)d_in[17];
    const float* cl_b2 = (const float*)d_in[18];

    char* ws = (char*)d_ws;
    ushort_t* xb     = (ushort_t*)(ws + OFF_XB);
    uchar_t*  h1f8   = (uchar_t*)(ws + OFF_H1F8);
    ushort_t* out1b  = (ushort_t*)(ws + OFF_OUT1B);
    uchar_t*  h2f8   = (uchar_t*)(ws + OFF_H2F8);
    float*    a1s    = (float*)(ws + OFF_A1S);
    float*    a1d    = (float*)(ws + OFF_A1D);
    float*    a2s    = (float*)(ws + OFF_A2S);
    float*    a2d    = (float*)(ws + OFF_A2D);
    int*      cnt    = (int*)(ws + OFF_CNT);
    float*    slots  = (float*)(ws + OFF_SLOTS);
    int*      rowptr = (int*)(ws + OFF_ROWPTR);
    int*      csr    = (int*)(ws + OFF_CSR);
    int*      part   = (int*)(ws + OFF_PART);
    ushort_t* w1t    = (ushort_t*)(ws + OFF_W1T);
    ushort_t* w2t    = (ushort_t*)(ws + OFF_W2T);
    int*      pos    = (int*)(ws + OFF_POS);

    const int npart = (N_NODES + 255) / 256;   // 196

    // single memset: cnt + slots contiguous
    hipMemsetAsync(cnt, 0, 200000 + N_GRAPHS * NSLOT * HID * sizeof(float), stream);

    prep_all<<<N_NODES * 256 / 4 / 256, 256, 0, stream>>>(
        x, xb, g1_w, g2_w, w1t, w2t, ei, cnt, pos);

    scan_partial<<<npart, 256, 0, stream>>>(cnt, part);
    scan_final2<<<npart, 256, 0, stream>>>(cnt, part, rowptr, npart);
    scatter_kernel<<<(N_EDGES + 255) / 256, 256, 0, stream>>>(ei, rowptr, pos, csr);

    // GAT1: h1(fp8) = x @ g1_w + fused att logits (f32)
    gemm1_swz<<<2 * ((N_NODES + 127) / 128), 256, 0, stream>>>(
        xb, w1t, h1f8, N_NODES, g1_as, g1_ad, a1s, a1d);
    gat1_agg<<<(N_NODES + 3) / 4, 256, 0, stream>>>(
        (const uint_t*)h1f8, a1s, a1d, rowptr, csr, g1_b, out1b);

    // GAT2: h2(fp8) = out1 @ g2_w + fused att logits; agg+pool
    gemm2_swz<<<(N_NODES + 127) / 128, 256, 0, stream>>>(
        out1b, w2t, h2f8, N_NODES, g2_as, g2_ad, a2s, a2d);
    gat2_agg_pool<<<N_NODES / 4, 256, 0, stream>>>(
        (const uint_t*)h2f8, a2s, a2d, rowptr, csr, g2_b, batch, slots);

    cls_kernel<<<N_GRAPHS, 64, 0, stream>>>(slots, batch, cl_w1, cl_b1, cl_w2, cl_b2, (float*)d_out);
}